// Round 9
// baseline (332.508 us; speedup 1.0000x reference)
//
#include <hip/hip_runtime.h>
#include <math.h>

#define Bq 4
#define Hq 512
#define Nq 64
#define Lq 2048
#define PARAM (Hq*Nq)   // 32768
#define T 64
#define NC (Lq/T)       // 32 chunks
#define NCOL 256        // 2 dirs * Bq * NC columns per h

// ---------------------------------------------------------------------------
// Phase 1: per-(h,n) parameter prep + power tables (two layouts).
//   pw [h][d][n]: (Re w^d, Im w^d), d=0..64   (delta/ktap/cscan: row-d access)
//   pwT[h][n][d]: same values transposed      (yact: lane-along-d coalesced)
// ---------------------------------------------------------------------------
__global__ void prep_kernel(const float* __restrict__ log_dt,
                            const float* __restrict__ log_A_real,
                            const float* __restrict__ A_imag,
                            const float* __restrict__ B_re, const float* __restrict__ B_im,
                            const float* __restrict__ C_re, const float* __restrict__ C_im,
                            float* __restrict__ a0, float* __restrict__ b0,
                            float* __restrict__ a1, float* __restrict__ b1,
                            float* __restrict__ pw, float* __restrict__ pwT) {
    int idx = blockIdx.x * blockDim.x + threadIdx.x;
    if (idx >= PARAM) return;
    int h = idx >> 6, n = idx & 63;
    float dt = expf(log_dt[h]);
    float Ar = -expf(log_A_real[idx]);
    float Ai = A_imag[idx];
    float er = expf(Ar * dt);
    float wr = er * cosf(Ai * dt);
    float wi = er * sinf(Ai * dt);
    float mr = wr - 1.0f, mi = wi;
    float den = Ar * Ar + Ai * Ai;
    float qr = (mr * Ar + mi * Ai) / den;
    float qi = (mi * Ar - mr * Ai) / den;
    float Br = B_re[idx], Bi = B_im[idx];
    float dBr = Br * qr - Bi * qi;
    float dBi = Br * qi + Bi * qr;
    float cr = C_re[idx], ci = C_im[idx];
    a0[idx] =  2.0f * (cr * dBr - ci * dBi);
    b0[idx] = -2.0f * (cr * dBi + ci * dBr);
    cr = C_re[PARAM + idx]; ci = C_im[PARAM + idx];
    a1[idx] =  2.0f * (cr * dBr - ci * dBi);
    b1[idx] = -2.0f * (cr * dBi + ci * dBr);
    float c = 1.f, s = 0.f;
    float* base  = pw  + (size_t)h * 65 * 128 + 2 * n;
    float* baseT = pwT + (size_t)(h * 64 + n) * 132;
    for (int d = 0; d <= 64; ++d) {
        *(float2*)(base + (size_t)d * 128) = float2{c, s};
        *(float2*)(baseT + 2 * d)          = float2{c, s};
        float nc = c * wr - s * wi;
        float ns = c * wi + s * wr;
        c = nc; s = ns;
    }
}

// ---------------------------------------------------------------------------
// Phase 1b: Toeplitz taps k[h][dir][d] = sum_n a*Re(w^d) + b*Im(w^d).
// ---------------------------------------------------------------------------
__global__ __launch_bounds__(128)
void ktap_kernel(const float* __restrict__ pw,
                 const float* __restrict__ a0, const float* __restrict__ b0,
                 const float* __restrict__ a1, const float* __restrict__ b1,
                 float* __restrict__ kt) {
    int h = blockIdx.x;
    int t = threadIdx.x;
    int dir = t >> 6, d = t & 63;
    const float* aa = dir ? a1 : a0;
    const float* bb = dir ? b1 : b0;
    const float* row = pw + (size_t)(h * 65 + d) * 128;
    float acc = 0.f;
    for (int n = 0; n < 64; ++n) {
        float2 v = *(const float2*)(row + 2 * n);
        acc = fmaf(aa[h * 64 + n], v.x, acc);
        acc = fmaf(bb[h * 64 + n], v.y, acc);
    }
    kt[((size_t)h * 2 + dir) * 64 + d] = acc;
}

// ---------------------------------------------------------------------------
// Phase 1c: WT[k][o] = W[o][k]  (1 MB; makes gemm W-staging coalesced and
// its LDS writes conflict-free).
// ---------------------------------------------------------------------------
__global__ __launch_bounds__(256)
void wtrans_kernel(const float* __restrict__ W, float* __restrict__ WT) {
    __shared__ float tile[64][65];
    int bo = blockIdx.x * 64;   // o-base
    int bk = blockIdx.y * 64;   // k-base
    int lx = threadIdx.x & 15;
    int ly = threadIdx.x >> 4;
    #pragma unroll
    for (int r = 0; r < 4; ++r) {
        float4 v = *(const float4*)(W + (size_t)(bo + ly + 16*r) * Hq + bk + 4*lx);
        tile[ly + 16*r][4*lx+0] = v.x;
        tile[ly + 16*r][4*lx+1] = v.y;
        tile[ly + 16*r][4*lx+2] = v.z;
        tile[ly + 16*r][4*lx+3] = v.w;
    }
    __syncthreads();
    #pragma unroll
    for (int r = 0; r < 4; ++r) {
        float4 v;
        v.x = tile[4*lx+0][ly + 16*r];
        v.y = tile[4*lx+1][ly + 16*r];
        v.z = tile[4*lx+2][ly + 16*r];
        v.w = tile[4*lx+3][ly + 16*r];
        *(float4*)(WT + (size_t)(bk + ly + 16*r) * Hq + bo + 4*lx) = v;
    }
}

// ---------------------------------------------------------------------------
// Phase 2: LayerNorm over channel dim H for each (b,l).  (unchanged)
// ---------------------------------------------------------------------------
__global__ __launch_bounds__(256)
void ln_kernel(const float* __restrict__ x, const float* __restrict__ lnw,
               const float* __restrict__ lnb, float* __restrict__ z) {
    int blk = blockIdx.x;
    int b  = blk / (Lq / 16);
    int l0 = (blk % (Lq / 16)) * 16;
    int tx = threadIdx.x & 15;
    int ty = threadIdx.x >> 4;
    const float* xb = x + (size_t)b * Hq * Lq;
    float s = 0.f, s2 = 0.f;
    for (int h = ty; h < Hq; h += 16) {
        float v = xb[h * Lq + l0 + tx];
        s += v; s2 += v * v;
    }
    __shared__ float rs_[16][17], r2_[16][17], mu_s[16], sg_s[16];
    rs_[ty][tx] = s; r2_[ty][tx] = s2;
    __syncthreads();
    if (ty == 0) {
        float a = 0.f, c = 0.f;
        #pragma unroll
        for (int i = 0; i < 16; ++i) { a += rs_[i][tx]; c += r2_[i][tx]; }
        float mu = a * (1.0f / Hq);
        float var = c * (1.0f / Hq) - mu * mu;
        mu_s[tx] = mu;
        sg_s[tx] = rsqrtf(var + 1e-5f);
    }
    __syncthreads();
    float mu = mu_s[tx], rs = sg_s[tx];
    float* zb = z + (size_t)b * Hq * Lq;
    for (int h = ty; h < Hq; h += 16) {
        float v = xb[h * Lq + l0 + tx];
        zb[h * Lq + l0 + tx] = (v - mu) * rs * lnw[h] + lnb[h];
    }
}

// ---------------------------------------------------------------------------
// delta GEMM (unchanged)
// ---------------------------------------------------------------------------
__global__ __launch_bounds__(256, 6)
void delta_kernel(const float* __restrict__ z, const float* __restrict__ pw,
                  float* __restrict__ buf) {
    __shared__ float Bs[64][68];
    int h = blockIdx.x, ct = blockIdx.y;
    int t = threadIdx.x;
    int dir = ct >> 1;
    int cc = t & 31, rb = (t >> 5) & 1, jg = t >> 6;
    int b = (ct & 1) * 2 + rb;
    const float* zb = z + ((size_t)b * Hq + h) * Lq;
    if (dir == 0) {
        #pragma unroll
        for (int f = 0; f < 4; ++f) {
            float4 v = *(const float4*)(zb + cc * 64 + 16 * jg + 4 * f);
            Bs[16*jg+4*f+0][rb*32+cc] = v.x;
            Bs[16*jg+4*f+1][rb*32+cc] = v.y;
            Bs[16*jg+4*f+2][rb*32+cc] = v.z;
            Bs[16*jg+4*f+3][rb*32+cc] = v.w;
        }
    } else {
        #pragma unroll
        for (int f = 0; f < 4; ++f) {
            float4 v = *(const float4*)(zb + 2044 - cc * 64 - 16 * jg - 4 * f);
            Bs[16*jg+4*f+3][rb*32+cc] = v.x;
            Bs[16*jg+4*f+2][rb*32+cc] = v.y;
            Bs[16*jg+4*f+1][rb*32+cc] = v.z;
            Bs[16*jg+4*f+0][rb*32+cc] = v.w;
        }
    }
    __syncthreads();
    int tx = t & 15, ty = t >> 4;
    float aR[4][4] = {}, aI[4][4] = {};
    const float* pwh = pw + (size_t)h * 65 * 128;
    #pragma unroll 4
    for (int kk = 0; kk < 64; ++kk) {
        int d = 63 - kk;
        const float4* pr = (const float4*)(pwh + (size_t)d * 128 + 8 * tx);
        float4 p0 = pr[0], p1 = pr[1];
        float4 bv = *(const float4*)&Bs[kk][4 * ty];
        float pc[4] = {p0.x, p0.z, p1.x, p1.z};
        float ps[4] = {p0.y, p0.w, p1.y, p1.w};
        #pragma unroll
        for (int rr = 0; rr < 4; ++rr) {
            #pragma unroll
            for (int q = 0; q < 4; ++q) {
                aR[rr][q] = fmaf(pc[rr], (&bv.x)[q], aR[rr][q]);
                aI[rr][q] = fmaf(ps[rr], (&bv.x)[q], aI[rr][q]);
            }
        }
    }
    #pragma unroll
    for (int q = 0; q < 4; ++q) {
        int colg = ct * 64 + 4 * ty + q;
        float* dst = buf + ((size_t)h * NCOL + colg) * 128 + 8 * tx;
        float4 v1, v2;
        v1.x = aR[0][q]; v1.y = aI[0][q]; v1.z = aR[1][q]; v1.w = aI[1][q];
        v2.x = aR[2][q]; v2.y = aI[2][q]; v2.z = aR[3][q]; v2.w = aI[3][q];
        *(float4*)dst = v1; *(float4*)(dst + 4) = v2;
    }
}

// ---------------------------------------------------------------------------
// inter-chunk scan (unchanged)
// ---------------------------------------------------------------------------
__global__ __launch_bounds__(256)
void cscan_kernel(const float* __restrict__ pw, float* __restrict__ buf) {
    int e = blockIdx.x * 4 + (threadIdx.x >> 6);
    int n = threadIdx.x & 63;
    int h = e >> 3, dir = (e >> 2) & 1, b = e & 3;
    float2 t64 = *(const float2*)(pw + (size_t)(h * 65 + 64) * 128 + 2 * n);
    float tc = t64.x, ts = t64.y;
    float sr = 0.f, si = 0.f;
    float2* p = (float2*)(buf + ((size_t)h * NCOL + dir * 128 + b * 32) * 128) + n;
    float2 d = p[0];
    for (int c = 0; c < NC; ++c) {
        float2 dn;
        if (c + 1 < NC) dn = p[(c + 1) * 64];
        float2 s; s.x = sr; s.y = si;
        p[c * 64] = s;
        float nr = fmaf(tc, sr, fmaf(-ts, si, d.x));
        float ni = fmaf(ts, sr, fmaf(tc, si, d.y));
        sr = nr; si = ni; d = dn;
    }
}

// ---------------------------------------------------------------------------
// Fused bidirectional Y GEMM + activation (unchanged from round 6)
// ---------------------------------------------------------------------------
__global__ __launch_bounds__(256, 4)
void yact_kernel(const float* __restrict__ z, const float* __restrict__ pwT,
                 const float* __restrict__ a0, const float* __restrict__ b0,
                 const float* __restrict__ a1, const float* __restrict__ b1,
                 const float* __restrict__ kt, const float* __restrict__ buf,
                 const float* __restrict__ Dv, float* __restrict__ u) {
    __shared__ float As[64][68];
    __shared__ float Bs[64][68];
    __shared__ float ks0[64], ks1[64], as0_[64], bs0_[64], as1_[64], bs1_[64];
    int h = blockIdx.x, bp = blockIdx.y;
    int t = threadIdx.x;
    if (t < 64) {
        ks0[t]  = kt[((size_t)h * 2 + 0) * 64 + t];
        ks1[t]  = kt[((size_t)h * 2 + 1) * 64 + t];
        as0_[t] = a0[h * 64 + t]; bs0_[t] = b0[h * 64 + t];
        as1_[t] = a1[h * 64 + t]; bs1_[t] = b1[h * 64 + t];
    }
    int tx = t & 15, ty = t >> 4;
    int si = t & 63, kg = t >> 6;
    int bS = 2 * bp + (si >> 5), ch = si & 31;
    const float* zb   = z + ((size_t)bS * Hq + h) * Lq + ch * 64;
    const float* bufh = buf + (size_t)h * NCOL * 128;
    const float* buf0 = bufh + (size_t)(bS * 32 + ch) * 128;
    const float* buf1 = bufh + (size_t)(128 + bS * 32 + (31 - ch)) * 128;
    const float* pwh  = pwT + (size_t)h * 64 * 132;
    float4 rB[4];
    float2 pv[8];
    #pragma unroll
    for (int f = 0; f < 4; ++f)
        rB[f] = *(const float4*)(zb + 16 * kg + 4 * f);
    float acc[4][4] = {};
    __syncthreads();
    for (int p = 0; p < 5; ++p) {
        if (p == 0) {
            #pragma unroll
            for (int q = 0; q < 16; ++q) {
                int kk = 16 * kg + q;
                int d = si - kk;
                As[kk][si] = (d >= 0) ? ks0[d] : ks1[-d - 1];
            }
        } else {
            const float* as_ = (p < 3) ? as0_ : as1_;
            const float* bs_ = (p < 3) ? bs0_ : bs1_;
            #pragma unroll
            for (int q = 0; q < 16; ++q) {
                int j = q >> 1;
                int n = 32 * ((p < 3) ? (p - 1) : (p - 3)) + 8 * kg + j;
                float vx = pv[j].x, vy = pv[j].y;
                As[16 * kg + q][si] = ((q & 1) == 0)
                    ? fmaf(as_[n], vx, bs_[n] * vy)
                    : fmaf(bs_[n], vx, -as_[n] * vy);
            }
        }
        #pragma unroll
        for (int f = 0; f < 4; ++f) {
            Bs[16*kg + 4*f + 0][si] = rB[f].x;
            Bs[16*kg + 4*f + 1][si] = rB[f].y;
            Bs[16*kg + 4*f + 2][si] = rB[f].z;
            Bs[16*kg + 4*f + 3][si] = rB[f].w;
        }
        __syncthreads();
        if (p < 4) {
            int pn = p + 1;
            int pp = (pn < 3) ? (pn - 1) : (pn - 3);
            const float* src = (pn < 3) ? buf0 : buf1;
            #pragma unroll
            for (int f = 0; f < 4; ++f)
                rB[f] = *(const float4*)(src + 64 * pp + 16 * kg + 4 * f);
            int dsel = (pn < 3) ? (si + 1) : (63 - si);
            #pragma unroll
            for (int j = 0; j < 8; ++j) {
                int n = 32 * pp + 8 * kg + j;
                pv[j] = *(const float2*)(pwh + (size_t)n * 132 + 2 * dsel);
            }
        }
        #pragma unroll 8
        for (int kk = 0; kk < 64; ++kk) {
            float4 av = *(const float4*)&As[kk][4 * tx];
            float4 bv = *(const float4*)&Bs[kk][4 * ty];
            #pragma unroll
            for (int ii = 0; ii < 4; ++ii) {
                float a = (&av.x)[ii];
                acc[ii][0] = fmaf(a, bv.x, acc[ii][0]);
                acc[ii][1] = fmaf(a, bv.y, acc[ii][1]);
                acc[ii][2] = fmaf(a, bv.z, acc[ii][2]);
                acc[ii][3] = fmaf(a, bv.w, acc[ii][3]);
            }
        }
        __syncthreads();
    }
    float dv = Dv[h];
    #pragma unroll
    for (int q = 0; q < 4; ++q) {
        int cc2 = 4 * ty + q;
        int b2 = 2 * bp + (cc2 >> 5), ch2 = cc2 & 31;
        size_t base = ((size_t)b2 * Hq + h) * Lq + ch2 * 64 + 4 * tx;
        float4 zr = *(const float4*)(z + base);
        float vv[4];
        vv[0] = acc[0][q] + dv * zr.x;
        vv[1] = acc[1][q] + dv * zr.y;
        vv[2] = acc[2][q] + dv * zr.z;
        vv[3] = acc[3][q] + dv * zr.w;
        #pragma unroll
        for (int i = 0; i < 4; ++i) {
            float v = vv[i];
            float tt = tanhf(0.7978845608028654f * (v + 0.044715f * v * v * v));
            vv[i] = 0.5f * v * (1.0f + tt);
        }
        float4 r; r.x = vv[0]; r.y = vv[1]; r.z = vv[2]; r.w = vv[3];
        *(float4*)(u + base) = r;
    }
}

// ---------------------------------------------------------------------------
// Phase 5: out = bias + x + WT^T@u.
// 256 threads, tile 128(o) x 64(l), BK=32 double-buffered, reg prefetch.
// Microtile 8o x 4l (two o-quadrants at +64): 48B LDS / 32 FMA = 1.5 B/FMA.
// Both stagings coalesced float4 row-writes (<=2-way banks, free).
// Grid 32x4x4 = 512 blocks = 2/CU, 8 waves/CU.
// ---------------------------------------------------------------------------
__global__ __launch_bounds__(256, 2)
void gemm_kernel(const float* __restrict__ u, const float* __restrict__ WT,
                 const float* __restrict__ bias, const float* __restrict__ x,
                 float* __restrict__ out) {
    __shared__ float Ws[2][32][132];
    __shared__ float Us[2][32][68];
    int l0 = blockIdx.x * 64;
    int o0 = blockIdx.y * 128;
    int b  = blockIdx.z;
    int t  = threadIdx.x;
    int tx = t & 15, ty = t >> 4;
    const float* ub = u + (size_t)b * Hq * Lq;
    int usf = t & 15, usk = t >> 4;      // u staging: 2 float4/thread
    int wsf = t & 31, wsk = t >> 5;      // w staging: 4 float4/thread
    float4 su[2], sw[4];
    #pragma unroll
    for (int r = 0; r < 2; ++r)
        su[r] = *(const float4*)(ub + (size_t)(usk + 16*r) * Lq + l0 + 4*usf);
    #pragma unroll
    for (int r = 0; r < 4; ++r)
        sw[r] = *(const float4*)(WT + (size_t)(wsk + 8*r) * Hq + o0 + 4*wsf);
    #pragma unroll
    for (int r = 0; r < 2; ++r)
        *(float4*)&Us[0][usk + 16*r][4*usf] = su[r];
    #pragma unroll
    for (int r = 0; r < 4; ++r)
        *(float4*)&Ws[0][wsk + 8*r][4*wsf] = sw[r];
    __syncthreads();
    float acc[2][4][4] = {};             // [oq][i][j]
    for (int kt = 0; kt < Hq / 32; ++kt) {
        int cur = kt & 1;
        if (kt < 15) {
            int k0 = (kt + 1) * 32;
            #pragma unroll
            for (int r = 0; r < 2; ++r)
                su[r] = *(const float4*)(ub + (size_t)(k0 + usk + 16*r) * Lq + l0 + 4*usf);
            #pragma unroll
            for (int r = 0; r < 4; ++r)
                sw[r] = *(const float4*)(WT + (size_t)(k0 + wsk + 8*r) * Hq + o0 + 4*wsf);
        }
        #pragma unroll 4
        for (int k = 0; k < 32; ++k) {
            float4 a0v = *(const float4*)&Ws[cur][k][4 * tx];
            float4 a1v = *(const float4*)&Ws[cur][k][64 + 4 * tx];
            float4 bv  = *(const float4*)&Us[cur][k][4 * ty];
            #pragma unroll
            for (int i = 0; i < 4; ++i) {
                float a0s = (&a0v.x)[i], a1s = (&a1v.x)[i];
                #pragma unroll
                for (int j = 0; j < 4; ++j) {
                    float bs = (&bv.x)[j];
                    acc[0][i][j] = fmaf(a0s, bs, acc[0][i][j]);
                    acc[1][i][j] = fmaf(a1s, bs, acc[1][i][j]);
                }
            }
        }
        if (kt < 15) {
            int nxt = cur ^ 1;
            #pragma unroll
            for (int r = 0; r < 2; ++r)
                *(float4*)&Us[nxt][usk + 16*r][4*usf] = su[r];
            #pragma unroll
            for (int r = 0; r < 4; ++r)
                *(float4*)&Ws[nxt][wsk + 8*r][4*wsf] = sw[r];
        }
        __syncthreads();
    }
    #pragma unroll
    for (int oq = 0; oq < 2; ++oq) {
        #pragma unroll
        for (int i = 0; i < 4; ++i) {
            int o = o0 + 64 * oq + 4 * tx + i;
            float bo = bias[o];
            size_t base = ((size_t)b * Hq + o) * Lq + l0 + 4 * ty;
            float4 xr = *(const float4*)(x + base);
            float4 r;
            r.x = acc[oq][i][0] + bo + xr.x;
            r.y = acc[oq][i][1] + bo + xr.y;
            r.z = acc[oq][i][2] + bo + xr.z;
            r.w = acc[oq][i][3] + bo + xr.w;
            *(float4*)(out + base) = r;
        }
    }
}

// ---------------------------------------------------------------------------
extern "C" void kernel_launch(void* const* d_in, const int* in_sizes, int n_in,
                              void* d_out, int out_size, void* d_ws, size_t ws_size,
                              hipStream_t stream) {
    (void)in_sizes; (void)n_in; (void)out_size; (void)ws_size;
    const float* x          = (const float*)d_in[0];
    const float* ln_w       = (const float*)d_in[1];
    const float* ln_b       = (const float*)d_in[2];
    const float* log_dt     = (const float*)d_in[3];
    const float* log_A_real = (const float*)d_in[4];
    const float* A_imag     = (const float*)d_in[5];
    const float* B_re       = (const float*)d_in[6];
    const float* B_im       = (const float*)d_in[7];
    const float* C_re       = (const float*)d_in[8];
    const float* C_im       = (const float*)d_in[9];
    const float* Dv         = (const float*)d_in[10];
    const float* W          = (const float*)d_in[11];
    const float* b_out      = (const float*)d_in[12];
    float* out = (float*)d_out;
    float* ws  = (float*)d_ws;

    const size_t BHL = (size_t)Bq * Hq * Lq;
    float* a0  = ws;
    float* b0  = ws + (size_t)PARAM;
    float* a1  = ws + 2 * (size_t)PARAM;
    float* b1  = ws + 3 * (size_t)PARAM;
    float* kt  = ws + 4 * (size_t)PARAM;
    float* pw  = ws + 6 * (size_t)PARAM;           // 512*65*128 = 130*PARAM
    float* pwT = ws + 136 * (size_t)PARAM;         // 512*64*132 = 132*PARAM
    float* wt  = ws + 268 * (size_t)PARAM;         // 512*512 = 8*PARAM
    float* z   = ws + 276 * (size_t)PARAM;
    float* u   = z  + BHL;
    float* buf = u + BHL;                          // 512*256*128 = 67 MB

    prep_kernel<<<PARAM / 256, 256, 0, stream>>>(log_dt, log_A_real, A_imag,
                                                 B_re, B_im, C_re, C_im,
                                                 a0, b0, a1, b1, pw, pwT);
    ln_kernel<<<Bq * (Lq / 16), 256, 0, stream>>>(x, ln_w, ln_b, z);
    ktap_kernel<<<Hq, 128, 0, stream>>>(pw, a0, b0, a1, b1, kt);
    wtrans_kernel<<<dim3(Hq / 64, Hq / 64), 256, 0, stream>>>(W, wt);
    delta_kernel<<<dim3(Hq, 4), 256, 0, stream>>>(z, pw, buf);
    cscan_kernel<<<Bq * Hq * 2 / 4, 256, 0, stream>>>(pw, buf);
    yact_kernel<<<dim3(Hq, 2), 256, 0, stream>>>(z, pwT, a0, b0, a1, b1,
                                                 kt, buf, Dv, u);
    gemm_kernel<<<dim3(Lq / 64, Hq / 128, Bq), 256, 0, stream>>>(u, wt, b_out, x, out);
}

// Round 10
// 299.405 us; speedup vs baseline: 1.1106x; 1.1106x over previous
//
#include <hip/hip_runtime.h>
#include <math.h>

#define Bq 4
#define Hq 512
#define Nq 64
#define Lq 2048
#define PARAM (Hq*Nq)   // 32768
#define T 64
#define NC (Lq/T)       // 32 chunks
#define NCOL 256        // 2 dirs * Bq * NC columns per h

// ---------------------------------------------------------------------------
// setup_kernel: blocks 0..127 = prep (params + power tables), 128..639 = ln.
//   pw [h][d][n]: (Re w^d, Im w^d), d=0..64
//   pwT[h][n][d]: transposed copy (yact lane-along-d coalesced)
// ---------------------------------------------------------------------------
__global__ __launch_bounds__(256)
void setup_kernel(const float* __restrict__ log_dt,
                  const float* __restrict__ log_A_real,
                  const float* __restrict__ A_imag,
                  const float* __restrict__ B_re, const float* __restrict__ B_im,
                  const float* __restrict__ C_re, const float* __restrict__ C_im,
                  float* __restrict__ a0, float* __restrict__ b0,
                  float* __restrict__ a1, float* __restrict__ b1,
                  float* __restrict__ pw, float* __restrict__ pwT,
                  const float* __restrict__ x, const float* __restrict__ lnw,
                  const float* __restrict__ lnb, float* __restrict__ z) {
    __shared__ float rs_[16][17], r2_[16][17], mu_s[16], sg_s[16];
    int bx = blockIdx.x;
    if (bx < 128) {
        // ---------------- prep ----------------
        int idx = bx * 256 + threadIdx.x;
        int h = idx >> 6, n = idx & 63;
        float dt = expf(log_dt[h]);
        float Ar = -expf(log_A_real[idx]);
        float Ai = A_imag[idx];
        float er = expf(Ar * dt);
        float wr = er * cosf(Ai * dt);
        float wi = er * sinf(Ai * dt);
        float mr = wr - 1.0f, mi = wi;
        float den = Ar * Ar + Ai * Ai;
        float qr = (mr * Ar + mi * Ai) / den;
        float qi = (mi * Ar - mr * Ai) / den;
        float Br = B_re[idx], Bi = B_im[idx];
        float dBr = Br * qr - Bi * qi;
        float dBi = Br * qi + Bi * qr;
        float cr = C_re[idx], ci = C_im[idx];
        a0[idx] =  2.0f * (cr * dBr - ci * dBi);
        b0[idx] = -2.0f * (cr * dBi + ci * dBr);
        cr = C_re[PARAM + idx]; ci = C_im[PARAM + idx];
        a1[idx] =  2.0f * (cr * dBr - ci * dBi);
        b1[idx] = -2.0f * (cr * dBi + ci * dBr);
        float c = 1.f, s = 0.f;
        float* base  = pw  + (size_t)h * 65 * 128 + 2 * n;
        float* baseT = pwT + (size_t)(h * 64 + n) * 132;
        for (int d = 0; d <= 64; ++d) {
            *(float2*)(base + (size_t)d * 128) = float2{c, s};
            *(float2*)(baseT + 2 * d)          = float2{c, s};
            float nc = c * wr - s * wi;
            float ns = c * wi + s * wr;
            c = nc; s = ns;
        }
        return;
    }
    // ---------------- layernorm ----------------
    int blk = bx - 128;
    int b  = blk / (Lq / 16);
    int l0 = (blk % (Lq / 16)) * 16;
    int tx = threadIdx.x & 15;
    int ty = threadIdx.x >> 4;
    const float* xb = x + (size_t)b * Hq * Lq;
    float s = 0.f, s2 = 0.f;
    for (int h = ty; h < Hq; h += 16) {
        float v = xb[h * Lq + l0 + tx];
        s += v; s2 += v * v;
    }
    rs_[ty][tx] = s; r2_[ty][tx] = s2;
    __syncthreads();
    if (ty == 0) {
        float a = 0.f, c = 0.f;
        #pragma unroll
        for (int i = 0; i < 16; ++i) { a += rs_[i][tx]; c += r2_[i][tx]; }
        float mu = a * (1.0f / Hq);
        float var = c * (1.0f / Hq) - mu * mu;
        mu_s[tx] = mu;
        sg_s[tx] = rsqrtf(var + 1e-5f);
    }
    __syncthreads();
    float mu = mu_s[tx], rs = sg_s[tx];
    float* zb = z + (size_t)b * Hq * Lq;
    for (int h = ty; h < Hq; h += 16) {
        float v = xb[h * Lq + l0 + tx];
        zb[h * Lq + l0 + tx] = (v - mu) * rs * lnw[h] + lnb[h];
    }
}

// ---------------------------------------------------------------------------
// deltascan_kernel: blockIdx.y<4 = delta GEMM + fused inter-chunk scan
// (writes s_init directly); blockIdx.y==4 = ktap (Toeplitz taps).
// A delta block (h,ct) owns ONE dir x 2 batches x all 32 chunks, so the
// inter-chunk scan closes inside the block via the Ds LDS tile.
// ---------------------------------------------------------------------------
__global__ __launch_bounds__(256, 3)
void deltascan_kernel(const float* __restrict__ z, const float* __restrict__ pw,
                      const float* __restrict__ a0, const float* __restrict__ b0,
                      const float* __restrict__ a1, const float* __restrict__ b1,
                      float* __restrict__ kt, float* __restrict__ buf) {
    __shared__ float Bs[64][68];
    __shared__ float Ds[64][130];   // [col-local][row 2n/2n+1]
    int h = blockIdx.x;
    int t = threadIdx.x;
    if (blockIdx.y == 4) {
        // ---------------- ktap ----------------
        if (t < 128) {
            int dir = t >> 6, d = t & 63;
            const float* aa = dir ? a1 : a0;
            const float* bb = dir ? b1 : b0;
            const float* row = pw + (size_t)(h * 65 + d) * 128;
            float acc = 0.f;
            for (int n = 0; n < 64; ++n) {
                float2 v = *(const float2*)(row + 2 * n);
                acc = fmaf(aa[h * 64 + n], v.x, acc);
                acc = fmaf(bb[h * 64 + n], v.y, acc);
            }
            kt[((size_t)h * 2 + dir) * 64 + d] = acc;
        }
        return;
    }
    int ct = blockIdx.y;
    int dir = ct >> 1;
    int cc = t & 31, rb = (t >> 5) & 1, jg = t >> 6;
    int b = (ct & 1) * 2 + rb;
    const float* zb = z + ((size_t)b * Hq + h) * Lq;
    if (dir == 0) {
        #pragma unroll
        for (int f = 0; f < 4; ++f) {
            float4 v = *(const float4*)(zb + cc * 64 + 16 * jg + 4 * f);
            Bs[16*jg+4*f+0][rb*32+cc] = v.x;
            Bs[16*jg+4*f+1][rb*32+cc] = v.y;
            Bs[16*jg+4*f+2][rb*32+cc] = v.z;
            Bs[16*jg+4*f+3][rb*32+cc] = v.w;
        }
    } else {
        #pragma unroll
        for (int f = 0; f < 4; ++f) {
            float4 v = *(const float4*)(zb + 2044 - cc * 64 - 16 * jg - 4 * f);
            Bs[16*jg+4*f+3][rb*32+cc] = v.x;
            Bs[16*jg+4*f+2][rb*32+cc] = v.y;
            Bs[16*jg+4*f+1][rb*32+cc] = v.z;
            Bs[16*jg+4*f+0][rb*32+cc] = v.w;
        }
    }
    __syncthreads();
    int tx = t & 15, ty = t >> 4;
    float aR[4][4] = {}, aI[4][4] = {};
    const float* pwh = pw + (size_t)h * 65 * 128;
    #pragma unroll 4
    for (int kk = 0; kk < 64; ++kk) {
        int d = 63 - kk;
        const float4* pr = (const float4*)(pwh + (size_t)d * 128 + 8 * tx);
        float4 p0 = pr[0], p1 = pr[1];
        float4 bv = *(const float4*)&Bs[kk][4 * ty];
        float pc[4] = {p0.x, p0.z, p1.x, p1.z};
        float ps[4] = {p0.y, p0.w, p1.y, p1.w};
        #pragma unroll
        for (int rr = 0; rr < 4; ++rr) {
            #pragma unroll
            for (int q = 0; q < 4; ++q) {
                aR[rr][q] = fmaf(pc[rr], (&bv.x)[q], aR[rr][q]);
                aI[rr][q] = fmaf(ps[rr], (&bv.x)[q], aI[rr][q]);
            }
        }
    }
    // deltas -> Ds
    #pragma unroll
    for (int q = 0; q < 4; ++q) {
        float* dst = &Ds[4 * ty + q][8 * tx];
        float4 v1, v2;
        v1.x = aR[0][q]; v1.y = aI[0][q]; v1.z = aR[1][q]; v1.w = aI[1][q];
        v2.x = aR[2][q]; v2.y = aI[2][q]; v2.z = aR[3][q]; v2.w = aI[3][q];
        *(float4*)dst = v1; *(float4*)(dst + 4) = v2;
    }
    __syncthreads();
    // in-place inter-chunk scan: 128 chains (2 b_local x 64 n), 32 steps.
    if (t < 128) {
        int bl = t >> 6, n = t & 63;
        float2 w64 = *(const float2*)(pw + (size_t)(h * 65 + 64) * 128 + 2 * n);
        float tc = w64.x, ts = w64.y;
        float sr = 0.f, si = 0.f;
        #pragma unroll 4
        for (int c = 0; c < NC; ++c) {
            int col = bl * 32 + c;
            float dr = Ds[col][2 * n], di = Ds[col][2 * n + 1];
            Ds[col][2 * n] = sr; Ds[col][2 * n + 1] = si;
            float nr = fmaf(tc, sr, fmaf(-ts, si, dr));
            float ni = fmaf(ts, sr, fmaf(tc, si, di));
            sr = nr; si = ni;
        }
    }
    __syncthreads();
    // s_init -> buf (coalesced)
    int colo = t >> 2, qg = t & 3;
    const float* srcd = &Ds[colo][qg * 32];
    float* dstg = buf + ((size_t)h * NCOL + ct * 64 + colo) * 128 + qg * 32;
    #pragma unroll
    for (int f = 0; f < 8; ++f)
        *(float4*)(dstg + 4 * f) = *(const float4*)(srcd + 4 * f);
}

// ---------------------------------------------------------------------------
// Fused bidirectional Y GEMM + activation (unchanged from round 6)
// ---------------------------------------------------------------------------
__global__ __launch_bounds__(256, 4)
void yact_kernel(const float* __restrict__ z, const float* __restrict__ pwT,
                 const float* __restrict__ a0, const float* __restrict__ b0,
                 const float* __restrict__ a1, const float* __restrict__ b1,
                 const float* __restrict__ kt, const float* __restrict__ buf,
                 const float* __restrict__ Dv, float* __restrict__ u) {
    __shared__ float As[64][68];
    __shared__ float Bs[64][68];
    __shared__ float ks0[64], ks1[64], as0_[64], bs0_[64], as1_[64], bs1_[64];
    int h = blockIdx.x, bp = blockIdx.y;
    int t = threadIdx.x;
    if (t < 64) {
        ks0[t]  = kt[((size_t)h * 2 + 0) * 64 + t];
        ks1[t]  = kt[((size_t)h * 2 + 1) * 64 + t];
        as0_[t] = a0[h * 64 + t]; bs0_[t] = b0[h * 64 + t];
        as1_[t] = a1[h * 64 + t]; bs1_[t] = b1[h * 64 + t];
    }
    int tx = t & 15, ty = t >> 4;
    int si = t & 63, kg = t >> 6;
    int bS = 2 * bp + (si >> 5), ch = si & 31;
    const float* zb   = z + ((size_t)bS * Hq + h) * Lq + ch * 64;
    const float* bufh = buf + (size_t)h * NCOL * 128;
    const float* buf0 = bufh + (size_t)(bS * 32 + ch) * 128;
    const float* buf1 = bufh + (size_t)(128 + bS * 32 + (31 - ch)) * 128;
    const float* pwh  = pwT + (size_t)h * 64 * 132;
    float4 rB[4];
    float2 pv[8];
    #pragma unroll
    for (int f = 0; f < 4; ++f)
        rB[f] = *(const float4*)(zb + 16 * kg + 4 * f);
    float acc[4][4] = {};
    __syncthreads();
    for (int p = 0; p < 5; ++p) {
        if (p == 0) {
            #pragma unroll
            for (int q = 0; q < 16; ++q) {
                int kk = 16 * kg + q;
                int d = si - kk;
                As[kk][si] = (d >= 0) ? ks0[d] : ks1[-d - 1];
            }
        } else {
            const float* as_ = (p < 3) ? as0_ : as1_;
            const float* bs_ = (p < 3) ? bs0_ : bs1_;
            #pragma unroll
            for (int q = 0; q < 16; ++q) {
                int j = q >> 1;
                int n = 32 * ((p < 3) ? (p - 1) : (p - 3)) + 8 * kg + j;
                float vx = pv[j].x, vy = pv[j].y;
                As[16 * kg + q][si] = ((q & 1) == 0)
                    ? fmaf(as_[n], vx, bs_[n] * vy)
                    : fmaf(bs_[n], vx, -as_[n] * vy);
            }
        }
        #pragma unroll
        for (int f = 0; f < 4; ++f) {
            Bs[16*kg + 4*f + 0][si] = rB[f].x;
            Bs[16*kg + 4*f + 1][si] = rB[f].y;
            Bs[16*kg + 4*f + 2][si] = rB[f].z;
            Bs[16*kg + 4*f + 3][si] = rB[f].w;
        }
        __syncthreads();
        if (p < 4) {
            int pn = p + 1;
            int pp = (pn < 3) ? (pn - 1) : (pn - 3);
            const float* src = (pn < 3) ? buf0 : buf1;
            #pragma unroll
            for (int f = 0; f < 4; ++f)
                rB[f] = *(const float4*)(src + 64 * pp + 16 * kg + 4 * f);
            int dsel = (pn < 3) ? (si + 1) : (63 - si);
            #pragma unroll
            for (int j = 0; j < 8; ++j) {
                int n = 32 * pp + 8 * kg + j;
                pv[j] = *(const float2*)(pwh + (size_t)n * 132 + 2 * dsel);
            }
        }
        #pragma unroll 8
        for (int kk = 0; kk < 64; ++kk) {
            float4 av = *(const float4*)&As[kk][4 * tx];
            float4 bv = *(const float4*)&Bs[kk][4 * ty];
            #pragma unroll
            for (int ii = 0; ii < 4; ++ii) {
                float a = (&av.x)[ii];
                acc[ii][0] = fmaf(a, bv.x, acc[ii][0]);
                acc[ii][1] = fmaf(a, bv.y, acc[ii][1]);
                acc[ii][2] = fmaf(a, bv.z, acc[ii][2]);
                acc[ii][3] = fmaf(a, bv.w, acc[ii][3]);
            }
        }
        __syncthreads();
    }
    float dv = Dv[h];
    #pragma unroll
    for (int q = 0; q < 4; ++q) {
        int cc2 = 4 * ty + q;
        int b2 = 2 * bp + (cc2 >> 5), ch2 = cc2 & 31;
        size_t base = ((size_t)b2 * Hq + h) * Lq + ch2 * 64 + 4 * tx;
        float4 zr = *(const float4*)(z + base);
        float vv[4];
        vv[0] = acc[0][q] + dv * zr.x;
        vv[1] = acc[1][q] + dv * zr.y;
        vv[2] = acc[2][q] + dv * zr.z;
        vv[3] = acc[3][q] + dv * zr.w;
        #pragma unroll
        for (int i = 0; i < 4; ++i) {
            float v = vv[i];
            float tt = tanhf(0.7978845608028654f * (v + 0.044715f * v * v * v));
            vv[i] = 0.5f * v * (1.0f + tt);
        }
        float4 r; r.x = vv[0]; r.y = vv[1]; r.z = vv[2]; r.w = vv[3];
        *(float4*)(u + base) = r;
    }
}

// ---------------------------------------------------------------------------
// Phase 5: out = bias + x + W@u.  (round-6 proven kernel, verbatim)
// 512 threads, tile 128(o) x 64(l), BK=32, double-buffered LDS,
// scalar reg prefetch (no float4 arrays -> no spill).
// ---------------------------------------------------------------------------
__global__ __launch_bounds__(512, 4)
void gemm_kernel(const float* __restrict__ u, const float* __restrict__ W,
                 const float* __restrict__ bias, const float* __restrict__ x,
                 float* __restrict__ out) {
    int l0 = blockIdx.x * 64;
    int o0 = blockIdx.y * 128;
    int b  = blockIdx.z;
    int tid = threadIdx.x;
    __shared__ float Ws[2][32][132];
    __shared__ float Us[2][32][68];
    const float* ub = u + (size_t)b * Hq * Lq;
    float acc[4][4] = {};
    int wo = tid >> 4, wl = tid & 15;
    int sj = tid & 31, so = tid >> 5;
    int sl = tid & 63, sk = tid >> 6;
    float wreg[8], ureg[4];
    #pragma unroll
    for (int r = 0; r < 8; ++r) wreg[r] = W[(size_t)(o0 + so + 16*r) * Hq + sj];
    #pragma unroll
    for (int r = 0; r < 4; ++r) ureg[r] = ub[(size_t)(4*sk + r) * Lq + l0 + sl];
    #pragma unroll
    for (int r = 0; r < 8; ++r) Ws[0][sj][so + 16*r] = wreg[r];
    #pragma unroll
    for (int r = 0; r < 4; ++r) Us[0][4*sk + r][sl] = ureg[r];
    __syncthreads();
    for (int t = 0; t < Hq / 32; ++t) {
        int cur = t & 1;
        if (t < 15) {
            int k0 = (t + 1) * 32;
            #pragma unroll
            for (int r = 0; r < 8; ++r)
                wreg[r] = W[(size_t)(o0 + so + 16*r) * Hq + k0 + sj];
            #pragma unroll
            for (int r = 0; r < 4; ++r)
                ureg[r] = ub[(size_t)(k0 + 4*sk + r) * Lq + l0 + sl];
        }
        #pragma unroll 8
        for (int j = 0; j < 32; ++j) {
            float4 av = *(const float4*)&Ws[cur][j][4 * wo];
            float4 bv = *(const float4*)&Us[cur][j][4 * wl];
            #pragma unroll
            for (int io = 0; io < 4; ++io) {
                float a = (&av.x)[io];
                acc[io][0] = fmaf(a, bv.x, acc[io][0]);
                acc[io][1] = fmaf(a, bv.y, acc[io][1]);
                acc[io][2] = fmaf(a, bv.z, acc[io][2]);
                acc[io][3] = fmaf(a, bv.w, acc[io][3]);
            }
        }
        if (t < 15) {
            int nxt = cur ^ 1;
            #pragma unroll
            for (int r = 0; r < 8; ++r) Ws[nxt][sj][so + 16*r] = wreg[r];
            #pragma unroll
            for (int r = 0; r < 4; ++r) Us[nxt][4*sk + r][sl] = ureg[r];
        }
        __syncthreads();
    }
    #pragma unroll
    for (int io = 0; io < 4; ++io) {
        int o = o0 + 4 * wo + io;
        float bo = bias[o];
        size_t base = ((size_t)b * Hq + o) * Lq + l0 + 4 * wl;
        const float4 xr = *(const float4*)(x + base);
        float4 r;
        r.x = acc[io][0] + bo + xr.x;
        r.y = acc[io][1] + bo + xr.y;
        r.z = acc[io][2] + bo + xr.z;
        r.w = acc[io][3] + bo + xr.w;
        *(float4*)(out + base) = r;
    }
}

// ---------------------------------------------------------------------------
extern "C" void kernel_launch(void* const* d_in, const int* in_sizes, int n_in,
                              void* d_out, int out_size, void* d_ws, size_t ws_size,
                              hipStream_t stream) {
    (void)in_sizes; (void)n_in; (void)out_size; (void)ws_size;
    const float* x          = (const float*)d_in[0];
    const float* ln_w       = (const float*)d_in[1];
    const float* ln_b       = (const float*)d_in[2];
    const float* log_dt     = (const float*)d_in[3];
    const float* log_A_real = (const float*)d_in[4];
    const float* A_imag     = (const float*)d_in[5];
    const float* B_re       = (const float*)d_in[6];
    const float* B_im       = (const float*)d_in[7];
    const float* C_re       = (const float*)d_in[8];
    const float* C_im       = (const float*)d_in[9];
    const float* Dv         = (const float*)d_in[10];
    const float* W          = (const float*)d_in[11];
    const float* b_out      = (const float*)d_in[12];
    float* out = (float*)d_out;
    float* ws  = (float*)d_ws;

    const size_t BHL = (size_t)Bq * Hq * Lq;
    float* a0  = ws;
    float* b0  = ws + (size_t)PARAM;
    float* a1  = ws + 2 * (size_t)PARAM;
    float* b1  = ws + 3 * (size_t)PARAM;
    float* kt  = ws + 4 * (size_t)PARAM;
    float* pw  = ws + 6 * (size_t)PARAM;           // 512*65*128 = 130*PARAM
    float* pwT = ws + 136 * (size_t)PARAM;         // 512*64*132 = 132*PARAM
    float* z   = ws + 268 * (size_t)PARAM;
    float* u   = z  + BHL;
    float* buf = u + BHL;                          // 512*256*128 = 67 MB

    setup_kernel<<<128 + Bq * (Lq / 16), 256, 0, stream>>>(
        log_dt, log_A_real, A_imag, B_re, B_im, C_re, C_im,
        a0, b0, a1, b1, pw, pwT, x, ln_w, ln_b, z);
    deltascan_kernel<<<dim3(Hq, 5), 256, 0, stream>>>(z, pw, a0, b0, a1, b1,
                                                      kt, buf);
    yact_kernel<<<dim3(Hq, 2), 256, 0, stream>>>(z, pwT, a0, b0, a1, b1,
                                                 kt, buf, Dv, u);
    gemm_kernel<<<dim3(Lq / 64, Hq / 128, Bq), 512, 0, stream>>>(u, W, b_out, x, out);
}

// Round 11
// 281.055 us; speedup vs baseline: 1.1831x; 1.0653x over previous
//
#include <hip/hip_runtime.h>
#include <math.h>

#define Bq 4
#define Hq 512
#define Nq 64
#define Lq 2048
#define PARAM (Hq*Nq)   // 32768

// ---------------------------------------------------------------------------
// setup_kernel: blocks 0..127 = prep (params + power tables), 128..639 = ln.
//   pw [h][d][n]: (Re w^d, Im w^d), d=0..64
//   pwT[h][n][d]: transposed copy (lane-along-d coalesced)
// ---------------------------------------------------------------------------
__global__ __launch_bounds__(256)
void setup_kernel(const float* __restrict__ log_dt,
                  const float* __restrict__ log_A_real,
                  const float* __restrict__ A_imag,
                  const float* __restrict__ B_re, const float* __restrict__ B_im,
                  const float* __restrict__ C_re, const float* __restrict__ C_im,
                  float* __restrict__ a0, float* __restrict__ b0,
                  float* __restrict__ a1, float* __restrict__ b1,
                  float* __restrict__ pw, float* __restrict__ pwT,
                  const float* __restrict__ x, const float* __restrict__ lnw,
                  const float* __restrict__ lnb, float* __restrict__ z) {
    __shared__ float rs_[16][17], r2_[16][17], mu_s[16], sg_s[16];
    int bx = blockIdx.x;
    if (bx < 128) {
        int idx = bx * 256 + threadIdx.x;
        int h = idx >> 6, n = idx & 63;
        float dt = expf(log_dt[h]);
        float Ar = -expf(log_A_real[idx]);
        float Ai = A_imag[idx];
        float er = expf(Ar * dt);
        float wr = er * cosf(Ai * dt);
        float wi = er * sinf(Ai * dt);
        float mr = wr - 1.0f, mi = wi;
        float den = Ar * Ar + Ai * Ai;
        float qr = (mr * Ar + mi * Ai) / den;
        float qi = (mi * Ar - mr * Ai) / den;
        float Br = B_re[idx], Bi = B_im[idx];
        float dBr = Br * qr - Bi * qi;
        float dBi = Br * qi + Bi * qr;
        float cr = C_re[idx], ci = C_im[idx];
        a0[idx] =  2.0f * (cr * dBr - ci * dBi);
        b0[idx] = -2.0f * (cr * dBi + ci * dBr);
        cr = C_re[PARAM + idx]; ci = C_im[PARAM + idx];
        a1[idx] =  2.0f * (cr * dBr - ci * dBi);
        b1[idx] = -2.0f * (cr * dBi + ci * dBr);
        float c = 1.f, s = 0.f;
        float* base  = pw  + (size_t)h * 65 * 128 + 2 * n;
        float* baseT = pwT + (size_t)(h * 64 + n) * 132;
        for (int d = 0; d <= 64; ++d) {
            *(float2*)(base + (size_t)d * 128) = float2{c, s};
            *(float2*)(baseT + 2 * d)          = float2{c, s};
            float nc = c * wr - s * wi;
            float ns = c * wi + s * wr;
            c = nc; s = ns;
        }
        return;
    }
    int blk = bx - 128;
    int b  = blk / (Lq / 16);
    int l0 = (blk % (Lq / 16)) * 16;
    int tx = threadIdx.x & 15;
    int ty = threadIdx.x >> 4;
    const float* xb = x + (size_t)b * Hq * Lq;
    float s = 0.f, s2 = 0.f;
    for (int h = ty; h < Hq; h += 16) {
        float v = xb[h * Lq + l0 + tx];
        s += v; s2 += v * v;
    }
    rs_[ty][tx] = s; r2_[ty][tx] = s2;
    __syncthreads();
    if (ty == 0) {
        float a = 0.f, c = 0.f;
        #pragma unroll
        for (int i = 0; i < 16; ++i) { a += rs_[i][tx]; c += r2_[i][tx]; }
        float mu = a * (1.0f / Hq);
        float var = c * (1.0f / Hq) - mu * mu;
        mu_s[tx] = mu;
        sg_s[tx] = rsqrtf(var + 1e-5f);
    }
    __syncthreads();
    float mu = mu_s[tx], rs = sg_s[tx];
    float* zb = z + (size_t)b * Hq * Lq;
    for (int h = ty; h < Hq; h += 16) {
        float v = xb[h * Lq + l0 + tx];
        zb[h * Lq + l0 + tx] = (v - mu) * rs * lnw[h] + lnb[h];
    }
}

// ---------------------------------------------------------------------------
// ssm_kernel: fused {ktap + delta GEMM (both dirs) + register chunk-scan +
// bidirectional Y GEMM + gelu}. Block (h, bp): 64 rows x 64 cols
// (2 batches x 32 physical chunks). States never touch HBM.
// Key identity: dir1 delta over reversed z == sum_j w^j * z_phys[j], so one
// physically-ordered Zs tile feeds both dirs AND the Toeplitz phase.
// ---------------------------------------------------------------------------
__global__ __launch_bounds__(256, 3)
void ssm_kernel(const float* __restrict__ z, const float* __restrict__ pw,
                const float* __restrict__ pwT,
                const float* __restrict__ a0, const float* __restrict__ b0,
                const float* __restrict__ a1, const float* __restrict__ b1,
                const float* __restrict__ Dv, float* __restrict__ u) {
    __shared__ float Zs[64][68];    // z tile, later reused as B (state) buffer
    __shared__ float As[64][68];    // A operand; scan V-buffer overlays this
    __shared__ float ks0[64], ks1[64], as0_[64], bs0_[64], as1_[64], bs1_[64];
    int h = blockIdx.x, bp = blockIdx.y;
    int t = threadIdx.x;
    int tx = t & 15, ty = t >> 4;
    const float* pwh  = pw  + (size_t)h * 65 * 128;
    const float* pwTh = pwT + (size_t)h * 64 * 132;
    // ---- stage Zs: Zs[j][col], col = bS*32 + pc (physical chunk) ----
    {
        int cc = t & 31, rb = (t >> 5) & 1, jg = t >> 6;
        const float* zb = z + ((size_t)(2 * bp + rb) * Hq + h) * Lq;
        #pragma unroll
        for (int f = 0; f < 4; ++f) {
            float4 v = *(const float4*)(zb + cc * 64 + 16 * jg + 4 * f);
            Zs[16*jg+4*f+0][rb*32+cc] = v.x;
            Zs[16*jg+4*f+1][rb*32+cc] = v.y;
            Zs[16*jg+4*f+2][rb*32+cc] = v.z;
            Zs[16*jg+4*f+3][rb*32+cc] = v.w;
        }
    }
    if (t < 64) {
        as0_[t] = a0[h*64+t]; bs0_[t] = b0[h*64+t];
        as1_[t] = a1[h*64+t]; bs1_[t] = b1[h*64+t];
    }
    __syncthreads();
    // ---- Toeplitz taps (ktap folded in; coalesced via pwT) ----
    if (t < 128) {
        int dir_ = t >> 6, d = t & 63;
        float acc2 = 0.f;
        if (dir_ == 0) {
            for (int n = 0; n < 64; ++n) {
                float2 v = *(const float2*)(pwTh + (size_t)n*132 + 2*d);
                acc2 = fmaf(as0_[n], v.x, acc2);
                acc2 = fmaf(bs0_[n], v.y, acc2);
            }
            ks0[d] = acc2;
        } else {
            for (int n = 0; n < 64; ++n) {
                float2 v = *(const float2*)(pwTh + (size_t)n*132 + 2*d);
                acc2 = fmaf(as1_[n], v.x, acc2);
                acc2 = fmaf(bs1_[n], v.y, acc2);
            }
            ks1[d] = acc2;
        }
    }
    // ---- delta GEMM, both dirs in one pass over z rows ----
    // d0[n][col] = sum_j w^(63-j) Zs[j][col] ; d1[n][col] = sum_j w^j Zs[j][col]
    float d0R[4][4] = {}, d0I[4][4] = {}, d1R[4][4] = {}, d1I[4][4] = {};
    #pragma unroll 2
    for (int j = 0; j < 64; ++j) {
        const float4* prA = (const float4*)(pwh + (size_t)(63-j)*128 + 8*tx);
        const float4* prB = (const float4*)(pwh + (size_t)j*128 + 8*tx);
        float4 pA0 = prA[0], pA1 = prA[1];
        float4 pB0 = prB[0], pB1 = prB[1];
        float4 zv = *(const float4*)&Zs[j][4*ty];
        float cA[4] = {pA0.x, pA0.z, pA1.x, pA1.z};
        float sA[4] = {pA0.y, pA0.w, pA1.y, pA1.w};
        float cB[4] = {pB0.x, pB0.z, pB1.x, pB1.z};
        float sB[4] = {pB0.y, pB0.w, pB1.y, pB1.w};
        #pragma unroll
        for (int rr = 0; rr < 4; ++rr) {
            #pragma unroll
            for (int q = 0; q < 4; ++q) {
                float zq = (&zv.x)[q];
                d0R[rr][q] = fmaf(cA[rr], zq, d0R[rr][q]);
                d0I[rr][q] = fmaf(sA[rr], zq, d0I[rr][q]);
                d1R[rr][q] = fmaf(cB[rr], zq, d1R[rr][q]);
                d1I[rr][q] = fmaf(sB[rr], zq, d1I[rr][q]);
            }
        }
    }
    // ---- chunk scan in registers (thread holds pc = 4g+q, g = ty&7) ----
    const float4* pr64 = (const float4*)(pwh + (size_t)64*128 + 8*tx);
    float4 w0v = pr64[0], w1v = pr64[1];
    float wc[4] = {w0v.x, w0v.z, w1v.x, w1v.z};
    float wn[4] = {w0v.y, w0v.w, w1v.y, w1v.w};
    int bS = ty >> 3, g = ty & 7;
    float* Vs = &As[0][0];          // [dir][bS][g][2n] with row stride 130
    #pragma unroll
    for (int rr = 0; rr < 4; ++rr) {     // pass 1: group folds V
        float vr = 0.f, vi = 0.f;
        #pragma unroll
        for (int q = 0; q < 4; ++q) {    // dir0: scan order q ascending
            float nr = fmaf(wc[rr], vr, fmaf(-wn[rr], vi, d0R[rr][q]));
            float ni = fmaf(wn[rr], vr, fmaf(wc[rr], vi, d0I[rr][q]));
            vr = nr; vi = ni;
        }
        *(float2*)(Vs + (size_t)((bS)*8+g)*130 + 2*(4*tx+rr)) = float2{vr, vi};
        vr = 0.f; vi = 0.f;
        #pragma unroll
        for (int q = 3; q >= 0; --q) {   // dir1: scan order q descending
            float nr = fmaf(wc[rr], vr, fmaf(-wn[rr], vi, d1R[rr][q]));
            float ni = fmaf(wn[rr], vr, fmaf(wc[rr], vi, d1I[rr][q]));
            vr = nr; vi = ni;
        }
        *(float2*)(Vs + (size_t)((2+bS)*8+g)*130 + 2*(4*tx+rr)) = float2{vr, vi};
    }
    __syncthreads();
    {   // group scan: one thread per (dir,bS,n) chain, ratio T = w64^4
        int dir_ = t >> 7, bS_ = (t >> 6) & 1, n_ = t & 63;
        float2 wv = *(const float2*)(pwh + (size_t)64*128 + 2*n_);
        float w2r = fmaf(wv.x, wv.x, -(wv.y*wv.y));
        float w2i = 2.f*wv.x*wv.y;
        float Tr = fmaf(w2r, w2r, -(w2i*w2i));
        float Ti = 2.f*w2r*w2i;
        float* row = Vs + (size_t)(dir_*2+bS_)*8*130 + 2*n_;
        float er = 0.f, ei = 0.f;
        #pragma unroll
        for (int s2 = 0; s2 < 8; ++s2) {
            int g2 = dir_ ? (7 - s2) : s2;
            float* p2 = row + g2*130;
            float vr2 = p2[0], vi2 = p2[1];
            p2[0] = er; p2[1] = ei;      // exclusive pre-group state E_g
            float nr = fmaf(Tr, er, fmaf(-Ti, ei, vr2));
            float ni = fmaf(Ti, er, fmaf(Tr, ei, vi2));
            er = nr; ei = ni;
        }
    }
    __syncthreads();
    #pragma unroll
    for (int rr = 0; rr < 4; ++rr) {     // pass 2: per-element init states
        float2 E0 = *(const float2*)(Vs + (size_t)((bS)*8+g)*130 + 2*(4*tx+rr));
        float trr = E0.x, tii = E0.y;
        #pragma unroll
        for (int q = 0; q < 4; ++q) {
            float dr = d0R[rr][q], di = d0I[rr][q];
            d0R[rr][q] = trr; d0I[rr][q] = tii;
            float nr = fmaf(wc[rr], trr, fmaf(-wn[rr], tii, dr));
            float ni = fmaf(wn[rr], trr, fmaf(wc[rr], tii, di));
            trr = nr; tii = ni;
        }
        float2 E1 = *(const float2*)(Vs + (size_t)((2+bS)*8+g)*130 + 2*(4*tx+rr));
        trr = E1.x; tii = E1.y;
        #pragma unroll
        for (int q = 3; q >= 0; --q) {
            float dr = d1R[rr][q], di = d1I[rr][q];
            d1R[rr][q] = trr; d1I[rr][q] = tii;
            float nr = fmaf(wc[rr], trr, fmaf(-wn[rr], tii, dr));
            float ni = fmaf(wn[rr], trr, fmaf(wc[rr], tii, di));
            trr = nr; tii = ni;
        }
    }
    __syncthreads();
    // ---- Y GEMM, 5 phases (p0 Toeplitz B=Zs; p1..4 states staged from regs) ----
    int si = t & 63, kg = t >> 6;
    float2 pv[8];
    float acc[4][4] = {};
    for (int p = 0; p < 5; ++p) {
        if (p == 0) {
            #pragma unroll
            for (int q = 0; q < 16; ++q) {
                int kk = 16*kg + q;
                int d = si - kk;
                As[kk][si] = (d >= 0) ? ks0[d] : ks1[-d-1];
            }
        } else {
            const float* as_ = (p < 3) ? as0_ : as1_;
            const float* bs_ = (p < 3) ? bs0_ : bs1_;
            #pragma unroll
            for (int q = 0; q < 16; ++q) {
                int j = q >> 1;
                int n = 32*((p < 3) ? (p-1) : (p-3)) + 8*kg + j;
                float vx = pv[j].x, vy = pv[j].y;
                As[16*kg+q][si] = ((q&1) == 0) ? fmaf(as_[n], vx, bs_[n]*vy)
                                               : fmaf(bs_[n], vx, -as_[n]*vy);
            }
            if (p == 1 && tx < 8) {
                #pragma unroll
                for (int rr = 0; rr < 4; ++rr) {
                    int ml = 8*tx + 2*rr;
                    #pragma unroll
                    for (int q = 0; q < 4; ++q) {
                        Zs[ml][4*ty+q]   = d0R[rr][q];
                        Zs[ml+1][4*ty+q] = d0I[rr][q];
                    }
                }
            } else if (p == 2 && tx >= 8) {
                #pragma unroll
                for (int rr = 0; rr < 4; ++rr) {
                    int ml = 8*(tx-8) + 2*rr;
                    #pragma unroll
                    for (int q = 0; q < 4; ++q) {
                        Zs[ml][4*ty+q]   = d0R[rr][q];
                        Zs[ml+1][4*ty+q] = d0I[rr][q];
                    }
                }
            } else if (p == 3 && tx < 8) {
                #pragma unroll
                for (int rr = 0; rr < 4; ++rr) {
                    int ml = 8*tx + 2*rr;
                    #pragma unroll
                    for (int q = 0; q < 4; ++q) {
                        Zs[ml][4*ty+q]   = d1R[rr][q];
                        Zs[ml+1][4*ty+q] = d1I[rr][q];
                    }
                }
            } else if (p == 4 && tx >= 8) {
                #pragma unroll
                for (int rr = 0; rr < 4; ++rr) {
                    int ml = 8*(tx-8) + 2*rr;
                    #pragma unroll
                    for (int q = 0; q < 4; ++q) {
                        Zs[ml][4*ty+q]   = d1R[rr][q];
                        Zs[ml+1][4*ty+q] = d1I[rr][q];
                    }
                }
            }
        }
        __syncthreads();
        if (p < 4) {
            int pn = p + 1;
            int pp = (pn < 3) ? (pn-1) : (pn-3);
            int dsel = (pn < 3) ? (si + 1) : (63 - si);
            #pragma unroll
            for (int j2 = 0; j2 < 8; ++j2) {
                int n = 32*pp + 8*kg + j2;
                pv[j2] = *(const float2*)(pwTh + (size_t)n*132 + 2*dsel);
            }
        }
        #pragma unroll 8
        for (int kk = 0; kk < 64; ++kk) {
            float4 av = *(const float4*)&As[kk][4*tx];
            float4 bv = *(const float4*)&Zs[kk][4*ty];
            #pragma unroll
            for (int ii = 0; ii < 4; ++ii) {
                float a = (&av.x)[ii];
                acc[ii][0] = fmaf(a, bv.x, acc[ii][0]);
                acc[ii][1] = fmaf(a, bv.y, acc[ii][1]);
                acc[ii][2] = fmaf(a, bv.z, acc[ii][2]);
                acc[ii][3] = fmaf(a, bv.w, acc[ii][3]);
            }
        }
        __syncthreads();
    }
    float dv = Dv[h];
    #pragma unroll
    for (int q = 0; q < 4; ++q) {
        int cc2 = 4*ty + q;
        int b2 = 2*bp + (cc2 >> 5), ch2 = cc2 & 31;
        size_t base = ((size_t)b2 * Hq + h) * Lq + ch2 * 64 + 4 * tx;
        float4 zr = *(const float4*)(z + base);
        float vv[4];
        vv[0] = acc[0][q] + dv * zr.x;
        vv[1] = acc[1][q] + dv * zr.y;
        vv[2] = acc[2][q] + dv * zr.z;
        vv[3] = acc[3][q] + dv * zr.w;
        #pragma unroll
        for (int i = 0; i < 4; ++i) {
            float v = vv[i];
            float tt = tanhf(0.7978845608028654f * (v + 0.044715f * v * v * v));
            vv[i] = 0.5f * v * (1.0f + tt);
        }
        float4 r; r.x = vv[0]; r.y = vv[1]; r.z = vv[2]; r.w = vv[3];
        *(float4*)(u + base) = r;
    }
}

// ---------------------------------------------------------------------------
// Phase 5: out = bias + x + W@u.  (round-6/10 proven kernel, verbatim)
// ---------------------------------------------------------------------------
__global__ __launch_bounds__(512, 4)
void gemm_kernel(const float* __restrict__ u, const float* __restrict__ W,
                 const float* __restrict__ bias, const float* __restrict__ x,
                 float* __restrict__ out) {
    int l0 = blockIdx.x * 64;
    int o0 = blockIdx.y * 128;
    int b  = blockIdx.z;
    int tid = threadIdx.x;
    __shared__ float Ws[2][32][132];
    __shared__ float Us[2][32][68];
    const float* ub = u + (size_t)b * Hq * Lq;
    float acc[4][4] = {};
    int wo = tid >> 4, wl = tid & 15;
    int sj = tid & 31, so = tid >> 5;
    int sl = tid & 63, sk = tid >> 6;
    float wreg[8], ureg[4];
    #pragma unroll
    for (int r = 0; r < 8; ++r) wreg[r] = W[(size_t)(o0 + so + 16*r) * Hq + sj];
    #pragma unroll
    for (int r = 0; r < 4; ++r) ureg[r] = ub[(size_t)(4*sk + r) * Lq + l0 + sl];
    #pragma unroll
    for (int r = 0; r < 8; ++r) Ws[0][sj][so + 16*r] = wreg[r];
    #pragma unroll
    for (int r = 0; r < 4; ++r) Us[0][4*sk + r][sl] = ureg[r];
    __syncthreads();
    for (int t = 0; t < Hq / 32; ++t) {
        int cur = t & 1;
        if (t < 15) {
            int k0 = (t + 1) * 32;
            #pragma unroll
            for (int r = 0; r < 8; ++r)
                wreg[r] = W[(size_t)(o0 + so + 16*r) * Hq + k0 + sj];
            #pragma unroll
            for (int r = 0; r < 4; ++r)
                ureg[r] = ub[(size_t)(k0 + 4*sk + r) * Lq + l0 + sl];
        }
        #pragma unroll 8
        for (int j = 0; j < 32; ++j) {
            float4 av = *(const float4*)&Ws[cur][j][4 * wo];
            float4 bv = *(const float4*)&Us[cur][j][4 * wl];
            #pragma unroll
            for (int io = 0; io < 4; ++io) {
                float a = (&av.x)[io];
                acc[io][0] = fmaf(a, bv.x, acc[io][0]);
                acc[io][1] = fmaf(a, bv.y, acc[io][1]);
                acc[io][2] = fmaf(a, bv.z, acc[io][2]);
                acc[io][3] = fmaf(a, bv.w, acc[io][3]);
            }
        }
        if (t < 15) {
            int nxt = cur ^ 1;
            #pragma unroll
            for (int r = 0; r < 8; ++r) Ws[nxt][sj][so + 16*r] = wreg[r];
            #pragma unroll
            for (int r = 0; r < 4; ++r) Us[nxt][4*sk + r][sl] = ureg[r];
        }
        __syncthreads();
    }
    #pragma unroll
    for (int io = 0; io < 4; ++io) {
        int o = o0 + 4 * wo + io;
        float bo = bias[o];
        size_t base = ((size_t)b * Hq + o) * Lq + l0 + 4 * wl;
        const float4 xr = *(const float4*)(x + base);
        float4 r;
        r.x = acc[io][0] + bo + xr.x;
        r.y = acc[io][1] + bo + xr.y;
        r.z = acc[io][2] + bo + xr.z;
        r.w = acc[io][3] + bo + xr.w;
        *(float4*)(out + base) = r;
    }
}

// ---------------------------------------------------------------------------
extern "C" void kernel_launch(void* const* d_in, const int* in_sizes, int n_in,
                              void* d_out, int out_size, void* d_ws, size_t ws_size,
                              hipStream_t stream) {
    (void)in_sizes; (void)n_in; (void)out_size; (void)ws_size;
    const float* x          = (const float*)d_in[0];
    const float* ln_w       = (const float*)d_in[1];
    const float* ln_b       = (const float*)d_in[2];
    const float* log_dt     = (const float*)d_in[3];
    const float* log_A_real = (const float*)d_in[4];
    const float* A_imag     = (const float*)d_in[5];
    const float* B_re       = (const float*)d_in[6];
    const float* B_im       = (const float*)d_in[7];
    const float* C_re       = (const float*)d_in[8];
    const float* C_im       = (const float*)d_in[9];
    const float* Dv         = (const float*)d_in[10];
    const float* W          = (const float*)d_in[11];
    const float* b_out      = (const float*)d_in[12];
    float* out = (float*)d_out;
    float* ws  = (float*)d_ws;

    const size_t BHL = (size_t)Bq * Hq * Lq;
    float* a0  = ws;
    float* b0  = ws + (size_t)PARAM;
    float* a1  = ws + 2 * (size_t)PARAM;
    float* b1  = ws + 3 * (size_t)PARAM;
    float* pw  = ws + 4 * (size_t)PARAM;           // 512*65*128 = 130*PARAM
    float* pwT = ws + 134 * (size_t)PARAM;         // 512*64*132 = 132*PARAM
    float* z   = ws + 266 * (size_t)PARAM;
    float* u   = z + BHL;

    setup_kernel<<<128 + Bq * (Lq / 16), 256, 0, stream>>>(
        log_dt, log_A_real, A_imag, B_re, B_im, C_re, C_im,
        a0, b0, a1, b1, pw, pwT, x, ln_w, ln_b, z);
    ssm_kernel<<<dim3(Hq, 2), 256, 0, stream>>>(z, pw, pwT, a0, b0, a1, b1,
                                                Dv, u);
    gemm_kernel<<<dim3(Lq / 64, Hq / 128, Bq), 512, 0, stream>>>(u, W, b_out, x, out);
}

// Round 12
// 276.284 us; speedup vs baseline: 1.2035x; 1.0173x over previous
//
#include <hip/hip_runtime.h>
#include <math.h>

#define Bq 4
#define Hq 512
#define Nq 64
#define Lq 2048
#define PARAM (Hq*Nq)   // 32768

// ---------------------------------------------------------------------------
// setup_kernel: blocks 0..127 = prep (params + power tables), 128..639 = ln.
//   pw [h][d][n]: (Re w^d, Im w^d), d=0..64
//   pwT[h][n][d]: transposed copy (lane-along-d coalesced)
// ---------------------------------------------------------------------------
__global__ __launch_bounds__(256)
void setup_kernel(const float* __restrict__ log_dt,
                  const float* __restrict__ log_A_real,
                  const float* __restrict__ A_imag,
                  const float* __restrict__ B_re, const float* __restrict__ B_im,
                  const float* __restrict__ C_re, const float* __restrict__ C_im,
                  float* __restrict__ a0, float* __restrict__ b0,
                  float* __restrict__ a1, float* __restrict__ b1,
                  float* __restrict__ pw, float* __restrict__ pwT,
                  const float* __restrict__ x, const float* __restrict__ lnw,
                  const float* __restrict__ lnb, float* __restrict__ z) {
    __shared__ float rs_[16][17], r2_[16][17], mu_s[16], sg_s[16];
    int bx = blockIdx.x;
    if (bx < 128) {
        int idx = bx * 256 + threadIdx.x;
        int h = idx >> 6, n = idx & 63;
        float dt = expf(log_dt[h]);
        float Ar = -expf(log_A_real[idx]);
        float Ai = A_imag[idx];
        float er = expf(Ar * dt);
        float wr = er * cosf(Ai * dt);
        float wi = er * sinf(Ai * dt);
        float mr = wr - 1.0f, mi = wi;
        float den = Ar * Ar + Ai * Ai;
        float qr = (mr * Ar + mi * Ai) / den;
        float qi = (mi * Ar - mr * Ai) / den;
        float Br = B_re[idx], Bi = B_im[idx];
        float dBr = Br * qr - Bi * qi;
        float dBi = Br * qi + Bi * qr;
        float cr = C_re[idx], ci = C_im[idx];
        a0[idx] =  2.0f * (cr * dBr - ci * dBi);
        b0[idx] = -2.0f * (cr * dBi + ci * dBr);
        cr = C_re[PARAM + idx]; ci = C_im[PARAM + idx];
        a1[idx] =  2.0f * (cr * dBr - ci * dBi);
        b1[idx] = -2.0f * (cr * dBi + ci * dBr);
        float c = 1.f, s = 0.f;
        float* base  = pw  + (size_t)h * 65 * 128 + 2 * n;
        float* baseT = pwT + (size_t)(h * 64 + n) * 132;
        for (int d = 0; d <= 64; ++d) {
            *(float2*)(base + (size_t)d * 128) = float2{c, s};
            *(float2*)(baseT + 2 * d)          = float2{c, s};
            float nc = c * wr - s * wi;
            float ns = c * wi + s * wr;
            c = nc; s = ns;
        }
        return;
    }
    int blk = bx - 128;
    int b  = blk / (Lq / 16);
    int l0 = (blk % (Lq / 16)) * 16;
    int tx = threadIdx.x & 15;
    int ty = threadIdx.x >> 4;
    const float* xb = x + (size_t)b * Hq * Lq;
    float s = 0.f, s2 = 0.f;
    for (int h = ty; h < Hq; h += 16) {
        float v = xb[h * Lq + l0 + tx];
        s += v; s2 += v * v;
    }
    rs_[ty][tx] = s; r2_[ty][tx] = s2;
    __syncthreads();
    if (ty == 0) {
        float a = 0.f, c = 0.f;
        #pragma unroll
        for (int i = 0; i < 16; ++i) { a += rs_[i][tx]; c += r2_[i][tx]; }
        float mu = a * (1.0f / Hq);
        float var = c * (1.0f / Hq) - mu * mu;
        mu_s[tx] = mu;
        sg_s[tx] = rsqrtf(var + 1e-5f);
    }
    __syncthreads();
    float mu = mu_s[tx], rs = sg_s[tx];
    float* zb = z + (size_t)b * Hq * Lq;
    for (int h = ty; h < Hq; h += 16) {
        float v = xb[h * Lq + l0 + tx];
        zb[h * Lq + l0 + tx] = (v - mu) * rs * lnw[h] + lnb[h];
    }
}

// ---------------------------------------------------------------------------
// ssm_kernel: fused {ktap + delta GEMM (both dirs) + register chunk-scan +
// bidirectional Y GEMM + gelu}. Block (h, bp): 64 rows x 64 cols
// (2 batches x 32 physical chunks). States never touch HBM.
// Delta pairing: one pw row k per step serves both dirs
//   (d0 += w^k * z[63-k], d1 += w^k * z[k]).
// ---------------------------------------------------------------------------
__global__ __launch_bounds__(256, 4)
void ssm_kernel(const float* __restrict__ z, const float* __restrict__ pw,
                const float* __restrict__ pwT,
                const float* __restrict__ a0, const float* __restrict__ b0,
                const float* __restrict__ a1, const float* __restrict__ b1,
                const float* __restrict__ Dv, float* __restrict__ u) {
    __shared__ float Zs[64][68];    // z tile, later reused as B (state) buffer
    __shared__ float As[64][68];    // A operand; scan V-buffer overlays this
    __shared__ float ks0[64], ks1[64], as0_[64], bs0_[64], as1_[64], bs1_[64];
    int h = blockIdx.x, bp = blockIdx.y;
    int t = threadIdx.x;
    int tx = t & 15, ty = t >> 4;
    const float* pwh  = pw  + (size_t)h * 65 * 128;
    const float* pwTh = pwT + (size_t)h * 64 * 132;
    // ---- stage Zs: Zs[j][col], col = bS*32 + pc (physical chunk) ----
    {
        int cc = t & 31, rb = (t >> 5) & 1, jg = t >> 6;
        const float* zb = z + ((size_t)(2 * bp + rb) * Hq + h) * Lq;
        #pragma unroll
        for (int f = 0; f < 4; ++f) {
            float4 v = *(const float4*)(zb + cc * 64 + 16 * jg + 4 * f);
            Zs[16*jg+4*f+0][rb*32+cc] = v.x;
            Zs[16*jg+4*f+1][rb*32+cc] = v.y;
            Zs[16*jg+4*f+2][rb*32+cc] = v.z;
            Zs[16*jg+4*f+3][rb*32+cc] = v.w;
        }
    }
    if (t < 64) {
        as0_[t] = a0[h*64+t]; bs0_[t] = b0[h*64+t];
        as1_[t] = a1[h*64+t]; bs1_[t] = b1[h*64+t];
    }
    __syncthreads();
    // ---- Toeplitz taps (coalesced via pwT) ----
    if (t < 128) {
        int dir_ = t >> 6, d = t & 63;
        float acc2 = 0.f;
        if (dir_ == 0) {
            for (int n = 0; n < 64; ++n) {
                float2 v = *(const float2*)(pwTh + (size_t)n*132 + 2*d);
                acc2 = fmaf(as0_[n], v.x, acc2);
                acc2 = fmaf(bs0_[n], v.y, acc2);
            }
            ks0[d] = acc2;
        } else {
            for (int n = 0; n < 64; ++n) {
                float2 v = *(const float2*)(pwTh + (size_t)n*132 + 2*d);
                acc2 = fmaf(as1_[n], v.x, acc2);
                acc2 = fmaf(bs1_[n], v.y, acc2);
            }
            ks1[d] = acc2;
        }
    }
    // ---- delta GEMM, both dirs, one pw row per step ----
    float d0R[4][4] = {}, d0I[4][4] = {}, d1R[4][4] = {}, d1I[4][4] = {};
    #pragma unroll 2
    for (int k = 0; k < 64; ++k) {
        const float4* pr = (const float4*)(pwh + (size_t)k*128 + 8*tx);
        float4 p0 = pr[0], p1 = pr[1];
        float c4[4] = {p0.x, p0.z, p1.x, p1.z};
        float s4[4] = {p0.y, p0.w, p1.y, p1.w};
        float4 zf = *(const float4*)&Zs[63-k][4*ty];   // d0 operand
        float4 zg = *(const float4*)&Zs[k][4*ty];      // d1 operand
        #pragma unroll
        for (int rr = 0; rr < 4; ++rr) {
            #pragma unroll
            for (int q = 0; q < 4; ++q) {
                float zq0 = (&zf.x)[q], zq1 = (&zg.x)[q];
                d0R[rr][q] = fmaf(c4[rr], zq0, d0R[rr][q]);
                d0I[rr][q] = fmaf(s4[rr], zq0, d0I[rr][q]);
                d1R[rr][q] = fmaf(c4[rr], zq1, d1R[rr][q]);
                d1I[rr][q] = fmaf(s4[rr], zq1, d1I[rr][q]);
            }
        }
    }
    // ---- chunk scan in registers (thread holds pc = 4g+q, g = ty&7) ----
    const float4* pr64 = (const float4*)(pwh + (size_t)64*128 + 8*tx);
    float4 w0v = pr64[0], w1v = pr64[1];
    float wc[4] = {w0v.x, w0v.z, w1v.x, w1v.z};
    float wn[4] = {w0v.y, w0v.w, w1v.y, w1v.w};
    int bS = ty >> 3, g = ty & 7;
    float* Vs = &As[0][0];          // [dir][bS][g][2n] with row stride 130
    #pragma unroll
    for (int rr = 0; rr < 4; ++rr) {     // pass 1: group folds V
        float vr = 0.f, vi = 0.f;
        #pragma unroll
        for (int q = 0; q < 4; ++q) {    // dir0: scan order q ascending
            float nr = fmaf(wc[rr], vr, fmaf(-wn[rr], vi, d0R[rr][q]));
            float ni = fmaf(wn[rr], vr, fmaf(wc[rr], vi, d0I[rr][q]));
            vr = nr; vi = ni;
        }
        *(float2*)(Vs + (size_t)((bS)*8+g)*130 + 2*(4*tx+rr)) = float2{vr, vi};
        vr = 0.f; vi = 0.f;
        #pragma unroll
        for (int q = 3; q >= 0; --q) {   // dir1: scan order q descending
            float nr = fmaf(wc[rr], vr, fmaf(-wn[rr], vi, d1R[rr][q]));
            float ni = fmaf(wn[rr], vr, fmaf(wc[rr], vi, d1I[rr][q]));
            vr = nr; vi = ni;
        }
        *(float2*)(Vs + (size_t)((2+bS)*8+g)*130 + 2*(4*tx+rr)) = float2{vr, vi};
    }
    __syncthreads();
    {   // group scan: one thread per (dir,bS,n) chain, ratio T = w64^4
        int dir_ = t >> 7, bS_ = (t >> 6) & 1, n_ = t & 63;
        float2 wv = *(const float2*)(pwh + (size_t)64*128 + 2*n_);
        float w2r = fmaf(wv.x, wv.x, -(wv.y*wv.y));
        float w2i = 2.f*wv.x*wv.y;
        float Tr = fmaf(w2r, w2r, -(w2i*w2i));
        float Ti = 2.f*w2r*w2i;
        float* row = Vs + (size_t)(dir_*2+bS_)*8*130 + 2*n_;
        float er = 0.f, ei = 0.f;
        #pragma unroll
        for (int s2 = 0; s2 < 8; ++s2) {
            int g2 = dir_ ? (7 - s2) : s2;
            float* p2 = row + g2*130;
            float vr2 = p2[0], vi2 = p2[1];
            p2[0] = er; p2[1] = ei;      // exclusive pre-group state E_g
            float nr = fmaf(Tr, er, fmaf(-Ti, ei, vr2));
            float ni = fmaf(Ti, er, fmaf(Tr, ei, vi2));
            er = nr; ei = ni;
        }
    }
    __syncthreads();
    #pragma unroll
    for (int rr = 0; rr < 4; ++rr) {     // pass 2: per-element init states
        float2 E0 = *(const float2*)(Vs + (size_t)((bS)*8+g)*130 + 2*(4*tx+rr));
        float trr = E0.x, tii = E0.y;
        #pragma unroll
        for (int q = 0; q < 4; ++q) {
            float dr = d0R[rr][q], di = d0I[rr][q];
            d0R[rr][q] = trr; d0I[rr][q] = tii;
            float nr = fmaf(wc[rr], trr, fmaf(-wn[rr], tii, dr));
            float ni = fmaf(wn[rr], trr, fmaf(wc[rr], tii, di));
            trr = nr; tii = ni;
        }
        float2 E1 = *(const float2*)(Vs + (size_t)((2+bS)*8+g)*130 + 2*(4*tx+rr));
        trr = E1.x; tii = E1.y;
        #pragma unroll
        for (int q = 3; q >= 0; --q) {
            float dr = d1R[rr][q], di = d1I[rr][q];
            d1R[rr][q] = trr; d1I[rr][q] = tii;
            float nr = fmaf(wc[rr], trr, fmaf(-wn[rr], tii, dr));
            float ni = fmaf(wn[rr], trr, fmaf(wc[rr], tii, di));
            trr = nr; tii = ni;
        }
    }
    __syncthreads();
    // ---- Y GEMM, 5 phases (p0 Toeplitz B=Zs; p1..4 states staged from regs) ----
    int si = t & 63, kg = t >> 6;
    float2 pv[8];
    float acc[4][4] = {};
    for (int p = 0; p < 5; ++p) {
        if (p == 0) {
            #pragma unroll
            for (int q = 0; q < 16; ++q) {
                int kk = 16*kg + q;
                int d = si - kk;
                As[kk][si] = (d >= 0) ? ks0[d] : ks1[-d-1];
            }
        } else {
            const float* as_ = (p < 3) ? as0_ : as1_;
            const float* bs_ = (p < 3) ? bs0_ : bs1_;
            #pragma unroll
            for (int q = 0; q < 16; ++q) {
                int j = q >> 1;
                int n = 32*((p < 3) ? (p-1) : (p-3)) + 8*kg + j;
                float vx = pv[j].x, vy = pv[j].y;
                As[16*kg+q][si] = ((q&1) == 0) ? fmaf(as_[n], vx, bs_[n]*vy)
                                               : fmaf(bs_[n], vx, -as_[n]*vy);
            }
            if (p == 1 && tx < 8) {
                #pragma unroll
                for (int rr = 0; rr < 4; ++rr) {
                    int ml = 8*tx + 2*rr;
                    float4 vR; vR.x = d0R[rr][0]; vR.y = d0R[rr][1];
                    vR.z = d0R[rr][2]; vR.w = d0R[rr][3];
                    float4 vI; vI.x = d0I[rr][0]; vI.y = d0I[rr][1];
                    vI.z = d0I[rr][2]; vI.w = d0I[rr][3];
                    *(float4*)&Zs[ml][4*ty]   = vR;
                    *(float4*)&Zs[ml+1][4*ty] = vI;
                }
            } else if (p == 2 && tx >= 8) {
                #pragma unroll
                for (int rr = 0; rr < 4; ++rr) {
                    int ml = 8*(tx-8) + 2*rr;
                    float4 vR; vR.x = d0R[rr][0]; vR.y = d0R[rr][1];
                    vR.z = d0R[rr][2]; vR.w = d0R[rr][3];
                    float4 vI; vI.x = d0I[rr][0]; vI.y = d0I[rr][1];
                    vI.z = d0I[rr][2]; vI.w = d0I[rr][3];
                    *(float4*)&Zs[ml][4*ty]   = vR;
                    *(float4*)&Zs[ml+1][4*ty] = vI;
                }
            } else if (p == 3 && tx < 8) {
                #pragma unroll
                for (int rr = 0; rr < 4; ++rr) {
                    int ml = 8*tx + 2*rr;
                    float4 vR; vR.x = d1R[rr][0]; vR.y = d1R[rr][1];
                    vR.z = d1R[rr][2]; vR.w = d1R[rr][3];
                    float4 vI; vI.x = d1I[rr][0]; vI.y = d1I[rr][1];
                    vI.z = d1I[rr][2]; vI.w = d1I[rr][3];
                    *(float4*)&Zs[ml][4*ty]   = vR;
                    *(float4*)&Zs[ml+1][4*ty] = vI;
                }
            } else if (p == 4 && tx >= 8) {
                #pragma unroll
                for (int rr = 0; rr < 4; ++rr) {
                    int ml = 8*(tx-8) + 2*rr;
                    float4 vR; vR.x = d1R[rr][0]; vR.y = d1R[rr][1];
                    vR.z = d1R[rr][2]; vR.w = d1R[rr][3];
                    float4 vI; vI.x = d1I[rr][0]; vI.y = d1I[rr][1];
                    vI.z = d1I[rr][2]; vI.w = d1I[rr][3];
                    *(float4*)&Zs[ml][4*ty]   = vR;
                    *(float4*)&Zs[ml+1][4*ty] = vI;
                }
            }
        }
        __syncthreads();
        if (p < 4) {
            int pn = p + 1;
            int pp = (pn < 3) ? (pn-1) : (pn-3);
            int dsel = (pn < 3) ? (si + 1) : (63 - si);
            #pragma unroll
            for (int j2 = 0; j2 < 8; ++j2) {
                int n = 32*pp + 8*kg + j2;
                pv[j2] = *(const float2*)(pwTh + (size_t)n*132 + 2*dsel);
            }
        }
        #pragma unroll 8
        for (int kk = 0; kk < 64; ++kk) {
            float4 av = *(const float4*)&As[kk][4*tx];
            float4 bv = *(const float4*)&Zs[kk][4*ty];
            #pragma unroll
            for (int ii = 0; ii < 4; ++ii) {
                float a = (&av.x)[ii];
                acc[ii][0] = fmaf(a, bv.x, acc[ii][0]);
                acc[ii][1] = fmaf(a, bv.y, acc[ii][1]);
                acc[ii][2] = fmaf(a, bv.z, acc[ii][2]);
                acc[ii][3] = fmaf(a, bv.w, acc[ii][3]);
            }
        }
        __syncthreads();
    }
    float dv = Dv[h];
    #pragma unroll
    for (int q = 0; q < 4; ++q) {
        int cc2 = 4*ty + q;
        int b2 = 2*bp + (cc2 >> 5), ch2 = cc2 & 31;
        size_t base = ((size_t)b2 * Hq + h) * Lq + ch2 * 64 + 4 * tx;
        float4 zr = *(const float4*)(z + base);
        float vv[4];
        vv[0] = acc[0][q] + dv * zr.x;
        vv[1] = acc[1][q] + dv * zr.y;
        vv[2] = acc[2][q] + dv * zr.z;
        vv[3] = acc[3][q] + dv * zr.w;
        #pragma unroll
        for (int i = 0; i < 4; ++i) {
            float v = vv[i];
            float tt = tanhf(0.7978845608028654f * (v + 0.044715f * v * v * v));
            vv[i] = 0.5f * v * (1.0f + tt);
        }
        float4 r; r.x = vv[0]; r.y = vv[1]; r.z = vv[2]; r.w = vv[3];
        *(float4*)(u + base) = r;
    }
}

// ---------------------------------------------------------------------------
// Phase 5: out = bias + x + W@u.  (round-6/10 proven kernel, verbatim —
// measured at the LDS per-lane roofline: 64.5 of 69 TB/s)
// ---------------------------------------------------------------------------
__global__ __launch_bounds__(512, 4)
void gemm_kernel(const float* __restrict__ u, const float* __restrict__ W,
                 const float* __restrict__ bias, const float* __restrict__ x,
                 float* __restrict__ out) {
    int l0 = blockIdx.x * 64;
    int o0 = blockIdx.y * 128;
    int b  = blockIdx.z;
    int tid = threadIdx.x;
    __shared__ float Ws[2][32][132];
    __shared__ float Us[2][32][68];
    const float* ub = u + (size_t)b * Hq * Lq;
    float acc[4][4] = {};
    int wo = tid >> 4, wl = tid & 15;
    int sj = tid & 31, so = tid >> 5;
    int sl = tid & 63, sk = tid >> 6;
    float wreg[8], ureg[4];
    #pragma unroll
    for (int r = 0; r < 8; ++r) wreg[r] = W[(size_t)(o0 + so + 16*r) * Hq + sj];
    #pragma unroll
    for (int r = 0; r < 4; ++r) ureg[r] = ub[(size_t)(4*sk + r) * Lq + l0 + sl];
    #pragma unroll
    for (int r = 0; r < 8; ++r) Ws[0][sj][so + 16*r] = wreg[r];
    #pragma unroll
    for (int r = 0; r < 4; ++r) Us[0][4*sk + r][sl] = ureg[r];
    __syncthreads();
    for (int t = 0; t < Hq / 32; ++t) {
        int cur = t & 1;
        if (t < 15) {
            int k0 = (t + 1) * 32;
            #pragma unroll
            for (int r = 0; r < 8; ++r)
                wreg[r] = W[(size_t)(o0 + so + 16*r) * Hq + k0 + sj];
            #pragma unroll
            for (int r = 0; r < 4; ++r)
                ureg[r] = ub[(size_t)(k0 + 4*sk + r) * Lq + l0 + sl];
        }
        #pragma unroll 8
        for (int j = 0; j < 32; ++j) {
            float4 av = *(const float4*)&Ws[cur][j][4 * wo];
            float4 bv = *(const float4*)&Us[cur][j][4 * wl];
            #pragma unroll
            for (int io = 0; io < 4; ++io) {
                float a = (&av.x)[io];
                acc[io][0] = fmaf(a, bv.x, acc[io][0]);
                acc[io][1] = fmaf(a, bv.y, acc[io][1]);
                acc[io][2] = fmaf(a, bv.z, acc[io][2]);
                acc[io][3] = fmaf(a, bv.w, acc[io][3]);
            }
        }
        if (t < 15) {
            int nxt = cur ^ 1;
            #pragma unroll
            for (int r = 0; r < 8; ++r) Ws[nxt][sj][so + 16*r] = wreg[r];
            #pragma unroll
            for (int r = 0; r < 4; ++r) Us[nxt][4*sk + r][sl] = ureg[r];
        }
        __syncthreads();
    }
    #pragma unroll
    for (int io = 0; io < 4; ++io) {
        int o = o0 + 4 * wo + io;
        float bo = bias[o];
        size_t base = ((size_t)b * Hq + o) * Lq + l0 + 4 * wl;
        const float4 xr = *(const float4*)(x + base);
        float4 r;
        r.x = acc[io][0] + bo + xr.x;
        r.y = acc[io][1] + bo + xr.y;
        r.z = acc[io][2] + bo + xr.z;
        r.w = acc[io][3] + bo + xr.w;
        *(float4*)(out + base) = r;
    }
}

// ---------------------------------------------------------------------------
extern "C" void kernel_launch(void* const* d_in, const int* in_sizes, int n_in,
                              void* d_out, int out_size, void* d_ws, size_t ws_size,
                              hipStream_t stream) {
    (void)in_sizes; (void)n_in; (void)out_size; (void)ws_size;
    const float* x          = (const float*)d_in[0];
    const float* ln_w       = (const float*)d_in[1];
    const float* ln_b       = (const float*)d_in[2];
    const float* log_dt     = (const float*)d_in[3];
    const float* log_A_real = (const float*)d_in[4];
    const float* A_imag     = (const float*)d_in[5];
    const float* B_re       = (const float*)d_in[6];
    const float* B_im       = (const float*)d_in[7];
    const float* C_re       = (const float*)d_in[8];
    const float* C_im       = (const float*)d_in[9];
    const float* Dv         = (const float*)d_in[10];
    const float* W          = (const float*)d_in[11];
    const float* b_out      = (const float*)d_in[12];
    float* out = (float*)d_out;
    float* ws  = (float*)d_ws;

    const size_t BHL = (size_t)Bq * Hq * Lq;
    float* a0  = ws;
    float* b0  = ws + (size_t)PARAM;
    float* a1  = ws + 2 * (size_t)PARAM;
    float* b1  = ws + 3 * (size_t)PARAM;
    float* pw  = ws + 4 * (size_t)PARAM;           // 512*65*128 = 130*PARAM
    float* pwT = ws + 134 * (size_t)PARAM;         // 512*64*132 = 132*PARAM
    float* z   = ws + 266 * (size_t)PARAM;
    float* u   = z + BHL;

    setup_kernel<<<128 + Bq * (Lq / 16), 256, 0, stream>>>(
        log_dt, log_A_real, A_imag, B_re, B_im, C_re, C_im,
        a0, b0, a1, b1, pw, pwT, x, ln_w, ln_b, z);
    ssm_kernel<<<dim3(Hq, 2), 256, 0, stream>>>(z, pw, pwT, a0, b0, a1, b1,
                                                Dv, u);
    gemm_kernel<<<dim3(Lq / 64, Hq / 128, Bq), 512, 0, stream>>>(u, W, b_out, x, out);
}

// Round 13
// 274.442 us; speedup vs baseline: 1.2116x; 1.0067x over previous
//
#include <hip/hip_runtime.h>
#include <math.h>

#define Bq 4
#define Hq 512
#define Nq 64
#define Lq 2048
#define PARAM (Hq*Nq)   // 32768

// Zs column swizzle: spreads state-staging writes across banks.
#define ZSW(row, col) ((col) ^ ((((row) >> 3) & 7) << 2))

// ---------------------------------------------------------------------------
// setup_kernel: blocks 0..127 = prep (params + power tables), 128..639 = ln.
//   pw [h][d][n]: (Re w^d, Im w^d), d=0..64
//   pwT[h][n][d]: transposed copy — written as contiguous 128B bursts from
//   a 16-power register chunk (kills 8B-scatter write amplification).
// ---------------------------------------------------------------------------
__global__ __launch_bounds__(256)
void setup_kernel(const float* __restrict__ log_dt,
                  const float* __restrict__ log_A_real,
                  const float* __restrict__ A_imag,
                  const float* __restrict__ B_re, const float* __restrict__ B_im,
                  const float* __restrict__ C_re, const float* __restrict__ C_im,
                  float* __restrict__ a0, float* __restrict__ b0,
                  float* __restrict__ a1, float* __restrict__ b1,
                  float* __restrict__ pw, float* __restrict__ pwT,
                  const float* __restrict__ x, const float* __restrict__ lnw,
                  const float* __restrict__ lnb, float* __restrict__ z) {
    __shared__ float rs_[16][17], r2_[16][17], mu_s[16], sg_s[16];
    int bx = blockIdx.x;
    if (bx < 128) {
        int idx = bx * 256 + threadIdx.x;
        int h = idx >> 6, n = idx & 63;
        float dt = expf(log_dt[h]);
        float Ar = -expf(log_A_real[idx]);
        float Ai = A_imag[idx];
        float er = expf(Ar * dt);
        float wr = er * cosf(Ai * dt);
        float wi = er * sinf(Ai * dt);
        float mr = wr - 1.0f, mi = wi;
        float den = Ar * Ar + Ai * Ai;
        float qr = (mr * Ar + mi * Ai) / den;
        float qi = (mi * Ar - mr * Ai) / den;
        float Br = B_re[idx], Bi = B_im[idx];
        float dBr = Br * qr - Bi * qi;
        float dBi = Br * qi + Bi * qr;
        float cr = C_re[idx], ci = C_im[idx];
        a0[idx] =  2.0f * (cr * dBr - ci * dBi);
        b0[idx] = -2.0f * (cr * dBi + ci * dBr);
        cr = C_re[PARAM + idx]; ci = C_im[PARAM + idx];
        a1[idx] =  2.0f * (cr * dBr - ci * dBi);
        b1[idx] = -2.0f * (cr * dBi + ci * dBr);
        float c = 1.f, s = 0.f;
        float* basep = pw  + (size_t)h * 65 * 128 + 2 * n;
        float* baset = pwT + (size_t)(h * 64 + n) * 132;
        #pragma unroll
        for (int ch = 0; ch < 4; ++ch) {
            float2 pr[16];
            #pragma unroll
            for (int dd = 0; dd < 16; ++dd) {
                pr[dd] = float2{c, s};
                float nc = c * wr - s * wi;
                float ns = c * wi + s * wr;
                c = nc; s = ns;
            }
            #pragma unroll
            for (int dd = 0; dd < 16; ++dd)
                *(float2*)(basep + (size_t)(ch * 16 + dd) * 128) = pr[dd];
            #pragma unroll
            for (int dd = 0; dd < 16; ++dd)
                *(float2*)(baset + 2 * (ch * 16 + dd)) = pr[dd];
        }
        *(float2*)(basep + (size_t)64 * 128) = float2{c, s};
        *(float2*)(baset + 128)              = float2{c, s};
        return;
    }
    int blk = bx - 128;
    int b  = blk / (Lq / 16);
    int l0 = (blk % (Lq / 16)) * 16;
    int tx = threadIdx.x & 15;
    int ty = threadIdx.x >> 4;
    const float* xb = x + (size_t)b * Hq * Lq;
    float s = 0.f, s2 = 0.f;
    for (int h = ty; h < Hq; h += 16) {
        float v = xb[h * Lq + l0 + tx];
        s += v; s2 += v * v;
    }
    rs_[ty][tx] = s; r2_[ty][tx] = s2;
    __syncthreads();
    if (ty == 0) {
        float a = 0.f, c = 0.f;
        #pragma unroll
        for (int i = 0; i < 16; ++i) { a += rs_[i][tx]; c += r2_[i][tx]; }
        float mu = a * (1.0f / Hq);
        float var = c * (1.0f / Hq) - mu * mu;
        mu_s[tx] = mu;
        sg_s[tx] = rsqrtf(var + 1e-5f);
    }
    __syncthreads();
    float mu = mu_s[tx], rs = sg_s[tx];
    float* zb = z + (size_t)b * Hq * Lq;
    for (int h = ty; h < Hq; h += 16) {
        float v = xb[h * Lq + l0 + tx];
        zb[h * Lq + l0 + tx] = (v - mu) * rs * lnw[h] + lnb[h];
    }
}

// ---------------------------------------------------------------------------
// ssm_kernel: fused {ktap + delta GEMM (both dirs) + register chunk-scan +
// bidirectional Y GEMM + gelu}. Block (h, bp): 64 rows x 64 cols.
// (256,3): no-spill point (r11: VGPR 80, WRITE clean). Zs accessed through
// ZSW swizzle everywhere -> staging conflicts 16-way -> 4-way.
// ---------------------------------------------------------------------------
__global__ __launch_bounds__(256, 3)
void ssm_kernel(const float* __restrict__ z, const float* __restrict__ pw,
                const float* __restrict__ pwT,
                const float* __restrict__ a0, const float* __restrict__ b0,
                const float* __restrict__ a1, const float* __restrict__ b1,
                const float* __restrict__ Dv, float* __restrict__ u) {
    __shared__ float Zs[64][68];    // z tile, later reused as B (state) buffer
    __shared__ float As[64][68];    // A operand; scan V-buffer overlays this
    __shared__ float ks0[64], ks1[64], as0_[64], bs0_[64], as1_[64], bs1_[64];
    int h = blockIdx.x, bp = blockIdx.y;
    int t = threadIdx.x;
    int tx = t & 15, ty = t >> 4;
    const float* pwh  = pw  + (size_t)h * 65 * 128;
    const float* pwTh = pwT + (size_t)h * 64 * 132;
    // ---- stage Zs (swizzled cols) ----
    {
        int cc = t & 31, rb = (t >> 5) & 1, jg = t >> 6;
        const float* zb = z + ((size_t)(2 * bp + rb) * Hq + h) * Lq;
        int c0 = rb * 32 + cc;
        #pragma unroll
        for (int f = 0; f < 4; ++f) {
            float4 v = *(const float4*)(zb + cc * 64 + 16 * jg + 4 * f);
            int r0 = 16*jg + 4*f;
            Zs[r0+0][ZSW(r0+0, c0)] = v.x;
            Zs[r0+1][ZSW(r0+1, c0)] = v.y;
            Zs[r0+2][ZSW(r0+2, c0)] = v.z;
            Zs[r0+3][ZSW(r0+3, c0)] = v.w;
        }
    }
    if (t < 64) {
        as0_[t] = a0[h*64+t]; bs0_[t] = b0[h*64+t];
        as1_[t] = a1[h*64+t]; bs1_[t] = b1[h*64+t];
    }
    __syncthreads();
    // ---- Toeplitz taps (coalesced via pwT) ----
    if (t < 128) {
        int dir_ = t >> 6, d = t & 63;
        float acc2 = 0.f;
        if (dir_ == 0) {
            for (int n = 0; n < 64; ++n) {
                float2 v = *(const float2*)(pwTh + (size_t)n*132 + 2*d);
                acc2 = fmaf(as0_[n], v.x, acc2);
                acc2 = fmaf(bs0_[n], v.y, acc2);
            }
            ks0[d] = acc2;
        } else {
            for (int n = 0; n < 64; ++n) {
                float2 v = *(const float2*)(pwTh + (size_t)n*132 + 2*d);
                acc2 = fmaf(as1_[n], v.x, acc2);
                acc2 = fmaf(bs1_[n], v.y, acc2);
            }
            ks1[d] = acc2;
        }
    }
    // ---- delta GEMM, both dirs, one pw row per step ----
    float d0R[4][4] = {}, d0I[4][4] = {}, d1R[4][4] = {}, d1I[4][4] = {};
    #pragma unroll 2
    for (int k = 0; k < 64; ++k) {
        const float4* pr = (const float4*)(pwh + (size_t)k*128 + 8*tx);
        float4 p0 = pr[0], p1 = pr[1];
        float c4[4] = {p0.x, p0.z, p1.x, p1.z};
        float s4[4] = {p0.y, p0.w, p1.y, p1.w};
        int rf = 63 - k;
        float4 zf = *(const float4*)&Zs[rf][ZSW(rf, 4*ty)];  // d0 operand
        float4 zg = *(const float4*)&Zs[k][ZSW(k, 4*ty)];    // d1 operand
        #pragma unroll
        for (int rr = 0; rr < 4; ++rr) {
            #pragma unroll
            for (int q = 0; q < 4; ++q) {
                float zq0 = (&zf.x)[q], zq1 = (&zg.x)[q];
                d0R[rr][q] = fmaf(c4[rr], zq0, d0R[rr][q]);
                d0I[rr][q] = fmaf(s4[rr], zq0, d0I[rr][q]);
                d1R[rr][q] = fmaf(c4[rr], zq1, d1R[rr][q]);
                d1I[rr][q] = fmaf(s4[rr], zq1, d1I[rr][q]);
            }
        }
    }
    // ---- chunk scan in registers (thread holds pc = 4g+q, g = ty&7) ----
    const float4* pr64 = (const float4*)(pwh + (size_t)64*128 + 8*tx);
    float4 w0v = pr64[0], w1v = pr64[1];
    float wc[4] = {w0v.x, w0v.z, w1v.x, w1v.z};
    float wn[4] = {w0v.y, w0v.w, w1v.y, w1v.w};
    int bS = ty >> 3, g = ty & 7;
    float* Vs = &As[0][0];          // [dir][bS][g][2n] with row stride 130
    #pragma unroll
    for (int rr = 0; rr < 4; ++rr) {     // pass 1: group folds V
        float vr = 0.f, vi = 0.f;
        #pragma unroll
        for (int q = 0; q < 4; ++q) {    // dir0: scan order q ascending
            float nr = fmaf(wc[rr], vr, fmaf(-wn[rr], vi, d0R[rr][q]));
            float ni = fmaf(wn[rr], vr, fmaf(wc[rr], vi, d0I[rr][q]));
            vr = nr; vi = ni;
        }
        *(float2*)(Vs + (size_t)((bS)*8+g)*130 + 2*(4*tx+rr)) = float2{vr, vi};
        vr = 0.f; vi = 0.f;
        #pragma unroll
        for (int q = 3; q >= 0; --q) {   // dir1: scan order q descending
            float nr = fmaf(wc[rr], vr, fmaf(-wn[rr], vi, d1R[rr][q]));
            float ni = fmaf(wn[rr], vr, fmaf(wc[rr], vi, d1I[rr][q]));
            vr = nr; vi = ni;
        }
        *(float2*)(Vs + (size_t)((2+bS)*8+g)*130 + 2*(4*tx+rr)) = float2{vr, vi};
    }
    __syncthreads();
    {   // group scan: one thread per (dir,bS,n) chain, ratio T = w64^4
        int dir_ = t >> 7, bS_ = (t >> 6) & 1, n_ = t & 63;
        float2 wv = *(const float2*)(pwh + (size_t)64*128 + 2*n_);
        float w2r = fmaf(wv.x, wv.x, -(wv.y*wv.y));
        float w2i = 2.f*wv.x*wv.y;
        float Tr = fmaf(w2r, w2r, -(w2i*w2i));
        float Ti = 2.f*w2r*w2i;
        float* row = Vs + (size_t)(dir_*2+bS_)*8*130 + 2*n_;
        float er = 0.f, ei = 0.f;
        #pragma unroll
        for (int s2 = 0; s2 < 8; ++s2) {
            int g2 = dir_ ? (7 - s2) : s2;
            float* p2 = row + g2*130;
            float vr2 = p2[0], vi2 = p2[1];
            p2[0] = er; p2[1] = ei;      // exclusive pre-group state E_g
            float nr = fmaf(Tr, er, fmaf(-Ti, ei, vr2));
            float ni = fmaf(Ti, er, fmaf(Tr, ei, vi2));
            er = nr; ei = ni;
        }
    }
    __syncthreads();
    #pragma unroll
    for (int rr = 0; rr < 4; ++rr) {     // pass 2: per-element init states
        float2 E0 = *(const float2*)(Vs + (size_t)((bS)*8+g)*130 + 2*(4*tx+rr));
        float trr = E0.x, tii = E0.y;
        #pragma unroll
        for (int q = 0; q < 4; ++q) {
            float dr = d0R[rr][q], di = d0I[rr][q];
            d0R[rr][q] = trr; d0I[rr][q] = tii;
            float nr = fmaf(wc[rr], trr, fmaf(-wn[rr], tii, dr));
            float ni = fmaf(wn[rr], trr, fmaf(wc[rr], tii, di));
            trr = nr; tii = ni;
        }
        float2 E1 = *(const float2*)(Vs + (size_t)((2+bS)*8+g)*130 + 2*(4*tx+rr));
        trr = E1.x; tii = E1.y;
        #pragma unroll
        for (int q = 3; q >= 0; --q) {
            float dr = d1R[rr][q], di = d1I[rr][q];
            d1R[rr][q] = trr; d1I[rr][q] = tii;
            float nr = fmaf(wc[rr], trr, fmaf(-wn[rr], tii, dr));
            float ni = fmaf(wn[rr], trr, fmaf(wc[rr], tii, di));
            trr = nr; tii = ni;
        }
    }
    __syncthreads();
    // ---- Y GEMM, 5 phases (p0 Toeplitz B=Zs; p1..4 states staged from regs) ----
    int si = t & 63, kg = t >> 6;
    float2 pv[8];
    float acc[4][4] = {};
    for (int p = 0; p < 5; ++p) {
        if (p == 0) {
            #pragma unroll
            for (int q = 0; q < 16; ++q) {
                int kk = 16*kg + q;
                int d = si - kk;
                As[kk][si] = (d >= 0) ? ks0[d] : ks1[-d-1];
            }
        } else {
            const float* as_ = (p < 3) ? as0_ : as1_;
            const float* bs_ = (p < 3) ? bs0_ : bs1_;
            #pragma unroll
            for (int q = 0; q < 16; ++q) {
                int j = q >> 1;
                int n = 32*((p < 3) ? (p-1) : (p-3)) + 8*kg + j;
                float vx = pv[j].x, vy = pv[j].y;
                As[16*kg+q][si] = ((q&1) == 0) ? fmaf(as_[n], vx, bs_[n]*vy)
                                               : fmaf(bs_[n], vx, -as_[n]*vy);
            }
            if (p == 1 && tx < 8) {
                #pragma unroll
                for (int rr = 0; rr < 4; ++rr) {
                    int ml = 8*tx + 2*rr;
                    float4 vR; vR.x = d0R[rr][0]; vR.y = d0R[rr][1];
                    vR.z = d0R[rr][2]; vR.w = d0R[rr][3];
                    float4 vI; vI.x = d0I[rr][0]; vI.y = d0I[rr][1];
                    vI.z = d0I[rr][2]; vI.w = d0I[rr][3];
                    *(float4*)&Zs[ml][ZSW(ml, 4*ty)]     = vR;
                    *(float4*)&Zs[ml+1][ZSW(ml+1, 4*ty)] = vI;
                }
            } else if (p == 2 && tx >= 8) {
                #pragma unroll
                for (int rr = 0; rr < 4; ++rr) {
                    int ml = 8*(tx-8) + 2*rr;
                    float4 vR; vR.x = d0R[rr][0]; vR.y = d0R[rr][1];
                    vR.z = d0R[rr][2]; vR.w = d0R[rr][3];
                    float4 vI; vI.x = d0I[rr][0]; vI.y = d0I[rr][1];
                    vI.z = d0I[rr][2]; vI.w = d0I[rr][3];
                    *(float4*)&Zs[ml][ZSW(ml, 4*ty)]     = vR;
                    *(float4*)&Zs[ml+1][ZSW(ml+1, 4*ty)] = vI;
                }
            } else if (p == 3 && tx < 8) {
                #pragma unroll
                for (int rr = 0; rr < 4; ++rr) {
                    int ml = 8*tx + 2*rr;
                    float4 vR; vR.x = d1R[rr][0]; vR.y = d1R[rr][1];
                    vR.z = d1R[rr][2]; vR.w = d1R[rr][3];
                    float4 vI; vI.x = d1I[rr][0]; vI.y = d1I[rr][1];
                    vI.z = d1I[rr][2]; vI.w = d1I[rr][3];
                    *(float4*)&Zs[ml][ZSW(ml, 4*ty)]     = vR;
                    *(float4*)&Zs[ml+1][ZSW(ml+1, 4*ty)] = vI;
                }
            } else if (p == 4 && tx >= 8) {
                #pragma unroll
                for (int rr = 0; rr < 4; ++rr) {
                    int ml = 8*(tx-8) + 2*rr;
                    float4 vR; vR.x = d1R[rr][0]; vR.y = d1R[rr][1];
                    vR.z = d1R[rr][2]; vR.w = d1R[rr][3];
                    float4 vI; vI.x = d1I[rr][0]; vI.y = d1I[rr][1];
                    vI.z = d1I[rr][2]; vI.w = d1I[rr][3];
                    *(float4*)&Zs[ml][ZSW(ml, 4*ty)]     = vR;
                    *(float4*)&Zs[ml+1][ZSW(ml+1, 4*ty)] = vI;
                }
            }
        }
        __syncthreads();
        if (p < 4) {
            int pn = p + 1;
            int pp = (pn < 3) ? (pn-1) : (pn-3);
            int dsel = (pn < 3) ? (si + 1) : (63 - si);
            #pragma unroll
            for (int j2 = 0; j2 < 8; ++j2) {
                int n = 32*pp + 8*kg + j2;
                pv[j2] = *(const float2*)(pwTh + (size_t)n*132 + 2*dsel);
            }
        }
        #pragma unroll 8
        for (int kk = 0; kk < 64; ++kk) {
            float4 av = *(const float4*)&As[kk][4*tx];
            float4 bv = *(const float4*)&Zs[kk][ZSW(kk, 4*ty)];
            #pragma unroll
            for (int ii = 0; ii < 4; ++ii) {
                float a = (&av.x)[ii];
                acc[ii][0] = fmaf(a, bv.x, acc[ii][0]);
                acc[ii][1] = fmaf(a, bv.y, acc[ii][1]);
                acc[ii][2] = fmaf(a, bv.z, acc[ii][2]);
                acc[ii][3] = fmaf(a, bv.w, acc[ii][3]);
            }
        }
        __syncthreads();
    }
    float dv = Dv[h];
    #pragma unroll
    for (int q = 0; q < 4; ++q) {
        int cc2 = 4*ty + q;
        int b2 = 2*bp + (cc2 >> 5), ch2 = cc2 & 31;
        size_t base = ((size_t)b2 * Hq + h) * Lq + ch2 * 64 + 4 * tx;
        float4 zr = *(const float4*)(z + base);
        float vv[4];
        vv[0] = acc[0][q] + dv * zr.x;
        vv[1] = acc[1][q] + dv * zr.y;
        vv[2] = acc[2][q] + dv * zr.z;
        vv[3] = acc[3][q] + dv * zr.w;
        #pragma unroll
        for (int i = 0; i < 4; ++i) {
            float v = vv[i];
            float tt = tanhf(0.7978845608028654f * (v + 0.044715f * v * v * v));
            vv[i] = 0.5f * v * (1.0f + tt);
        }
        float4 r; r.x = vv[0]; r.y = vv[1]; r.z = vv[2]; r.w = vv[3];
        *(float4*)(u + base) = r;
    }
}

// ---------------------------------------------------------------------------
// Phase 5: out = bias + x + W@u.  (round-6/10 proven kernel, verbatim —
// measured at the LDS per-lane roofline: 64.5 of 69 TB/s)
// ---------------------------------------------------------------------------
__global__ __launch_bounds__(512, 4)
void gemm_kernel(const float* __restrict__ u, const float* __restrict__ W,
                 const float* __restrict__ bias, const float* __restrict__ x,
                 float* __restrict__ out) {
    int l0 = blockIdx.x * 64;
    int o0 = blockIdx.y * 128;
    int b  = blockIdx.z;
    int tid = threadIdx.x;
    __shared__ float Ws[2][32][132];
    __shared__ float Us[2][32][68];
    const float* ub = u + (size_t)b * Hq * Lq;
    float acc[4][4] = {};
    int wo = tid >> 4, wl = tid & 15;
    int sj = tid & 31, so = tid >> 5;
    int sl = tid & 63, sk = tid >> 6;
    float wreg[8], ureg[4];
    #pragma unroll
    for (int r = 0; r < 8; ++r) wreg[r] = W[(size_t)(o0 + so + 16*r) * Hq + sj];
    #pragma unroll
    for (int r = 0; r < 4; ++r) ureg[r] = ub[(size_t)(4*sk + r) * Lq + l0 + sl];
    #pragma unroll
    for (int r = 0; r < 8; ++r) Ws[0][sj][so + 16*r] = wreg[r];
    #pragma unroll
    for (int r = 0; r < 4; ++r) Us[0][4*sk + r][sl] = ureg[r];
    __syncthreads();
    for (int t = 0; t < Hq / 32; ++t) {
        int cur = t & 1;
        if (t < 15) {
            int k0 = (t + 1) * 32;
            #pragma unroll
            for (int r = 0; r < 8; ++r)
                wreg[r] = W[(size_t)(o0 + so + 16*r) * Hq + k0 + sj];
            #pragma unroll
            for (int r = 0; r < 4; ++r)
                ureg[r] = ub[(size_t)(k0 + 4*sk + r) * Lq + l0 + sl];
        }
        #pragma unroll 8
        for (int j = 0; j < 32; ++j) {
            float4 av = *(const float4*)&Ws[cur][j][4 * wo];
            float4 bv = *(const float4*)&Us[cur][j][4 * wl];
            #pragma unroll
            for (int io = 0; io < 4; ++io) {
                float a = (&av.x)[io];
                acc[io][0] = fmaf(a, bv.x, acc[io][0]);
                acc[io][1] = fmaf(a, bv.y, acc[io][1]);
                acc[io][2] = fmaf(a, bv.z, acc[io][2]);
                acc[io][3] = fmaf(a, bv.w, acc[io][3]);
            }
        }
        if (t < 15) {
            int nxt = cur ^ 1;
            #pragma unroll
            for (int r = 0; r < 8; ++r) Ws[nxt][sj][so + 16*r] = wreg[r];
            #pragma unroll
            for (int r = 0; r < 4; ++r) Us[nxt][4*sk + r][sl] = ureg[r];
        }
        __syncthreads();
    }
    #pragma unroll
    for (int io = 0; io < 4; ++io) {
        int o = o0 + 4 * wo + io;
        float bo = bias[o];
        size_t base = ((size_t)b * Hq + o) * Lq + l0 + 4 * wl;
        const float4 xr = *(const float4*)(x + base);
        float4 r;
        r.x = acc[io][0] + bo + xr.x;
        r.y = acc[io][1] + bo + xr.y;
        r.z = acc[io][2] + bo + xr.z;
        r.w = acc[io][3] + bo + xr.w;
        *(float4*)(out + base) = r;
    }
}

// ---------------------------------------------------------------------------
extern "C" void kernel_launch(void* const* d_in, const int* in_sizes, int n_in,
                              void* d_out, int out_size, void* d_ws, size_t ws_size,
                              hipStream_t stream) {
    (void)in_sizes; (void)n_in; (void)out_size; (void)ws_size;
    const float* x          = (const float*)d_in[0];
    const float* ln_w       = (const float*)d_in[1];
    const float* ln_b       = (const float*)d_in[2];
    const float* log_dt     = (const float*)d_in[3];
    const float* log_A_real = (const float*)d_in[4];
    const float* A_imag     = (const float*)d_in[5];
    const float* B_re       = (const float*)d_in[6];
    const float* B_im       = (const float*)d_in[7];
    const float* C_re       = (const float*)d_in[8];
    const float* C_im       = (const float*)d_in[9];
    const float* Dv         = (const float*)d_in[10];
    const float* W          = (const float*)d_in[11];
    const float* b_out      = (const float*)d_in[12];
    float* out = (float*)d_out;
    float* ws  = (float*)d_ws;

    const size_t BHL = (size_t)Bq * Hq * Lq;
    float* a0  = ws;
    float* b0  = ws + (size_t)PARAM;
    float* a1  = ws + 2 * (size_t)PARAM;
    float* b1  = ws + 3 * (size_t)PARAM;
    float* pw  = ws + 4 * (size_t)PARAM;           // 512*65*128 = 130*PARAM
    float* pwT = ws + 134 * (size_t)PARAM;         // 512*64*132 = 132*PARAM
    float* z   = ws + 266 * (size_t)PARAM;
    float* u   = z + BHL;

    setup_kernel<<<128 + Bq * (Lq / 16), 256, 0, stream>>>(
        log_dt, log_A_real, A_imag, B_re, B_im, C_re, C_im,
        a0, b0, a1, b1, pw, pwT, x, ln_w, ln_b, z);
    ssm_kernel<<<dim3(Hq, 2), 256, 0, stream>>>(z, pw, pwT, a0, b0, a1, b1,
                                                Dv, u);
    gemm_kernel<<<dim3(Lq / 64, Hq / 128, Bq), 512, 0, stream>>>(u, W, b_out, x, out);
}

// Round 14
// 272.634 us; speedup vs baseline: 1.2196x; 1.0066x over previous
//
#include <hip/hip_runtime.h>
#include <math.h>

#define Bq 4
#define Hq 512
#define Nq 64
#define Lq 2048
#define PARAM (Hq*Nq)   // 32768

// Zs column swizzle: spreads state-staging writes across banks.
#define ZSW(row, col) ((col) ^ ((((row) >> 3) & 7) << 2))

// ---------------------------------------------------------------------------
// setup_kernel: blocks 0..127 = prep (params + power tables),
//               blocks 128..255 = LN over (b, 64-l tile), float4-vectorized.
// ---------------------------------------------------------------------------
__global__ __launch_bounds__(256)
void setup_kernel(const float* __restrict__ log_dt,
                  const float* __restrict__ log_A_real,
                  const float* __restrict__ A_imag,
                  const float* __restrict__ B_re, const float* __restrict__ B_im,
                  const float* __restrict__ C_re, const float* __restrict__ C_im,
                  float* __restrict__ a0, float* __restrict__ b0,
                  float* __restrict__ a1, float* __restrict__ b1,
                  float* __restrict__ pw, float* __restrict__ pwT,
                  const float* __restrict__ x, const float* __restrict__ lnw,
                  const float* __restrict__ lnb, float* __restrict__ z) {
    __shared__ float4 rs4[16][17], r24[16][17];
    __shared__ float mu_s[64], sg_s[64];
    int bx = blockIdx.x;
    if (bx < 128) {
        // ---------------- prep ----------------
        int idx = bx * 256 + threadIdx.x;
        int h = idx >> 6, n = idx & 63;
        float dt = expf(log_dt[h]);
        float Ar = -expf(log_A_real[idx]);
        float Ai = A_imag[idx];
        float er = expf(Ar * dt);
        float wr = er * cosf(Ai * dt);
        float wi = er * sinf(Ai * dt);
        float mr = wr - 1.0f, mi = wi;
        float den = Ar * Ar + Ai * Ai;
        float qr = (mr * Ar + mi * Ai) / den;
        float qi = (mi * Ar - mr * Ai) / den;
        float Br = B_re[idx], Bi = B_im[idx];
        float dBr = Br * qr - Bi * qi;
        float dBi = Br * qi + Bi * qr;
        float cr = C_re[idx], ci = C_im[idx];
        a0[idx] =  2.0f * (cr * dBr - ci * dBi);
        b0[idx] = -2.0f * (cr * dBi + ci * dBr);
        cr = C_re[PARAM + idx]; ci = C_im[PARAM + idx];
        a1[idx] =  2.0f * (cr * dBr - ci * dBi);
        b1[idx] = -2.0f * (cr * dBi + ci * dBr);
        float c = 1.f, s = 0.f;
        float* basep = pw  + (size_t)h * 65 * 128 + 2 * n;
        float* baset = pwT + (size_t)(h * 64 + n) * 132;
        #pragma unroll
        for (int ch = 0; ch < 4; ++ch) {
            float2 pr[16];
            #pragma unroll
            for (int dd = 0; dd < 16; ++dd) {
                pr[dd] = float2{c, s};
                float nc = c * wr - s * wi;
                float ns = c * wi + s * wr;
                c = nc; s = ns;
            }
            #pragma unroll
            for (int dd = 0; dd < 16; ++dd)
                *(float2*)(basep + (size_t)(ch * 16 + dd) * 128) = pr[dd];
            #pragma unroll
            for (int dd = 0; dd < 16; ++dd)
                *(float2*)(baset + 2 * (ch * 16 + dd)) = pr[dd];
        }
        *(float2*)(basep + (size_t)64 * 128) = float2{c, s};
        *(float2*)(baset + 128)              = float2{c, s};
        return;
    }
    // ---------------- layernorm, float4 over l ----------------
    int blk = bx - 128;              // 0..127
    int b  = blk >> 5;               // batch
    int l0 = (blk & 31) * 64;        // 64-l tile
    int tx = threadIdx.x & 15;       // float4 lane: l = l0 + 4*tx + q
    int ty = threadIdx.x >> 4;       // h group
    const float* xb = x + (size_t)b * Hq * Lq;
    float4 s  = {0.f, 0.f, 0.f, 0.f};
    float4 s2 = {0.f, 0.f, 0.f, 0.f};
    for (int h = ty; h < Hq; h += 16) {
        float4 v = *(const float4*)(xb + (size_t)h * Lq + l0 + 4 * tx);
        s.x += v.x; s.y += v.y; s.z += v.z; s.w += v.w;
        s2.x = fmaf(v.x, v.x, s2.x); s2.y = fmaf(v.y, v.y, s2.y);
        s2.z = fmaf(v.z, v.z, s2.z); s2.w = fmaf(v.w, v.w, s2.w);
    }
    rs4[ty][tx] = s; r24[ty][tx] = s2;
    __syncthreads();
    if (ty == 0) {
        float4 a = {0.f, 0.f, 0.f, 0.f};
        float4 c = {0.f, 0.f, 0.f, 0.f};
        #pragma unroll
        for (int i = 0; i < 16; ++i) {
            float4 va = rs4[i][tx], vc = r24[i][tx];
            a.x += va.x; a.y += va.y; a.z += va.z; a.w += va.w;
            c.x += vc.x; c.y += vc.y; c.z += vc.z; c.w += vc.w;
        }
        #pragma unroll
        for (int q = 0; q < 4; ++q) {
            float mu = (&a.x)[q] * (1.0f / Hq);
            float var = (&c.x)[q] * (1.0f / Hq) - mu * mu;
            mu_s[4 * tx + q] = mu;
            sg_s[4 * tx + q] = rsqrtf(var + 1e-5f);
        }
    }
    __syncthreads();
    float4 mu4, sg4;
    mu4.x = mu_s[4*tx+0]; mu4.y = mu_s[4*tx+1];
    mu4.z = mu_s[4*tx+2]; mu4.w = mu_s[4*tx+3];
    sg4.x = sg_s[4*tx+0]; sg4.y = sg_s[4*tx+1];
    sg4.z = sg_s[4*tx+2]; sg4.w = sg_s[4*tx+3];
    float* zb = z + (size_t)b * Hq * Lq;
    for (int h = ty; h < Hq; h += 16) {
        float4 v = *(const float4*)(xb + (size_t)h * Lq + l0 + 4 * tx);
        float w = lnw[h], bb = lnb[h];
        float4 r;
        r.x = fmaf((v.x - mu4.x) * sg4.x, w, bb);
        r.y = fmaf((v.y - mu4.y) * sg4.y, w, bb);
        r.z = fmaf((v.z - mu4.z) * sg4.z, w, bb);
        r.w = fmaf((v.w - mu4.w) * sg4.w, w, bb);
        *(float4*)(zb + (size_t)h * Lq + l0 + 4 * tx) = r;
    }
}

// ---------------------------------------------------------------------------
// ssm_kernel: fused {ktap + delta GEMM (both dirs) + register chunk-scan +
// bidirectional Y GEMM + gelu}. Block (h, bp): 64 rows x 64 cols.
// Delta loop now prefetches pw row k+1 into regs (hides L2 latency at the
// 2-wave/SIMD occupancy this kernel runs at).
// ---------------------------------------------------------------------------
__global__ __launch_bounds__(256, 3)
void ssm_kernel(const float* __restrict__ z, const float* __restrict__ pw,
                const float* __restrict__ pwT,
                const float* __restrict__ a0, const float* __restrict__ b0,
                const float* __restrict__ a1, const float* __restrict__ b1,
                const float* __restrict__ Dv, float* __restrict__ u) {
    __shared__ float Zs[64][68];    // z tile, later reused as B (state) buffer
    __shared__ float As[64][68];    // A operand; scan V-buffer overlays this
    __shared__ float ks0[64], ks1[64], as0_[64], bs0_[64], as1_[64], bs1_[64];
    int h = blockIdx.x, bp = blockIdx.y;
    int t = threadIdx.x;
    int tx = t & 15, ty = t >> 4;
    const float* pwh  = pw  + (size_t)h * 65 * 128;
    const float* pwTh = pwT + (size_t)h * 64 * 132;
    // ---- stage Zs (swizzled cols) ----
    {
        int cc = t & 31, rb = (t >> 5) & 1, jg = t >> 6;
        const float* zb = z + ((size_t)(2 * bp + rb) * Hq + h) * Lq;
        int c0 = rb * 32 + cc;
        #pragma unroll
        for (int f = 0; f < 4; ++f) {
            float4 v = *(const float4*)(zb + cc * 64 + 16 * jg + 4 * f);
            int r0 = 16*jg + 4*f;
            Zs[r0+0][ZSW(r0+0, c0)] = v.x;
            Zs[r0+1][ZSW(r0+1, c0)] = v.y;
            Zs[r0+2][ZSW(r0+2, c0)] = v.z;
            Zs[r0+3][ZSW(r0+3, c0)] = v.w;
        }
    }
    if (t < 64) {
        as0_[t] = a0[h*64+t]; bs0_[t] = b0[h*64+t];
        as1_[t] = a1[h*64+t]; bs1_[t] = b1[h*64+t];
    }
    __syncthreads();
    // ---- Toeplitz taps (coalesced via pwT) ----
    if (t < 128) {
        int dir_ = t >> 6, d = t & 63;
        float acc2 = 0.f;
        if (dir_ == 0) {
            for (int n = 0; n < 64; ++n) {
                float2 v = *(const float2*)(pwTh + (size_t)n*132 + 2*d);
                acc2 = fmaf(as0_[n], v.x, acc2);
                acc2 = fmaf(bs0_[n], v.y, acc2);
            }
            ks0[d] = acc2;
        } else {
            for (int n = 0; n < 64; ++n) {
                float2 v = *(const float2*)(pwTh + (size_t)n*132 + 2*d);
                acc2 = fmaf(as1_[n], v.x, acc2);
                acc2 = fmaf(bs1_[n], v.y, acc2);
            }
            ks1[d] = acc2;
        }
    }
    // ---- delta GEMM, both dirs, one pw row per step, prefetched ----
    float d0R[4][4] = {}, d0I[4][4] = {}, d1R[4][4] = {}, d1I[4][4] = {};
    float4 p0, p1;
    {
        const float4* pr = (const float4*)(pwh + 8*tx);
        p0 = pr[0]; p1 = pr[1];
    }
    #pragma unroll 2
    for (int k = 0; k < 64; ++k) {
        float4 n0 = p0, n1 = p1;
        if (k < 63) {
            const float4* prn = (const float4*)(pwh + (size_t)(k+1)*128 + 8*tx);
            n0 = prn[0]; n1 = prn[1];
        }
        float c4[4] = {p0.x, p0.z, p1.x, p1.z};
        float s4[4] = {p0.y, p0.w, p1.y, p1.w};
        int rf = 63 - k;
        float4 zf = *(const float4*)&Zs[rf][ZSW(rf, 4*ty)];  // d0 operand
        float4 zg = *(const float4*)&Zs[k][ZSW(k, 4*ty)];    // d1 operand
        #pragma unroll
        for (int rr = 0; rr < 4; ++rr) {
            #pragma unroll
            for (int q = 0; q < 4; ++q) {
                float zq0 = (&zf.x)[q], zq1 = (&zg.x)[q];
                d0R[rr][q] = fmaf(c4[rr], zq0, d0R[rr][q]);
                d0I[rr][q] = fmaf(s4[rr], zq0, d0I[rr][q]);
                d1R[rr][q] = fmaf(c4[rr], zq1, d1R[rr][q]);
                d1I[rr][q] = fmaf(s4[rr], zq1, d1I[rr][q]);
            }
        }
        p0 = n0; p1 = n1;
    }
    // ---- chunk scan in registers (thread holds pc = 4g+q, g = ty&7) ----
    const float4* pr64 = (const float4*)(pwh + (size_t)64*128 + 8*tx);
    float4 w0v = pr64[0], w1v = pr64[1];
    float wc[4] = {w0v.x, w0v.z, w1v.x, w1v.z};
    float wn[4] = {w0v.y, w0v.w, w1v.y, w1v.w};
    int bS = ty >> 3, g = ty & 7;
    float* Vs = &As[0][0];          // [dir][bS][g][2n] with row stride 130
    #pragma unroll
    for (int rr = 0; rr < 4; ++rr) {     // pass 1: group folds V
        float vr = 0.f, vi = 0.f;
        #pragma unroll
        for (int q = 0; q < 4; ++q) {    // dir0: scan order q ascending
            float nr = fmaf(wc[rr], vr, fmaf(-wn[rr], vi, d0R[rr][q]));
            float ni = fmaf(wn[rr], vr, fmaf(wc[rr], vi, d0I[rr][q]));
            vr = nr; vi = ni;
        }
        *(float2*)(Vs + (size_t)((bS)*8+g)*130 + 2*(4*tx+rr)) = float2{vr, vi};
        vr = 0.f; vi = 0.f;
        #pragma unroll
        for (int q = 3; q >= 0; --q) {   // dir1: scan order q descending
            float nr = fmaf(wc[rr], vr, fmaf(-wn[rr], vi, d1R[rr][q]));
            float ni = fmaf(wn[rr], vr, fmaf(wc[rr], vi, d1I[rr][q]));
            vr = nr; vi = ni;
        }
        *(float2*)(Vs + (size_t)((2+bS)*8+g)*130 + 2*(4*tx+rr)) = float2{vr, vi};
    }
    __syncthreads();
    {   // group scan: one thread per (dir,bS,n) chain, ratio T = w64^4
        int dir_ = t >> 7, bS_ = (t >> 6) & 1, n_ = t & 63;
        float2 wv = *(const float2*)(pwh + (size_t)64*128 + 2*n_);
        float w2r = fmaf(wv.x, wv.x, -(wv.y*wv.y));
        float w2i = 2.f*wv.x*wv.y;
        float Tr = fmaf(w2r, w2r, -(w2i*w2i));
        float Ti = 2.f*w2r*w2i;
        float* row = Vs + (size_t)(dir_*2+bS_)*8*130 + 2*n_;
        float er = 0.f, ei = 0.f;
        #pragma unroll
        for (int s2 = 0; s2 < 8; ++s2) {
            int g2 = dir_ ? (7 - s2) : s2;
            float* p2 = row + g2*130;
            float vr2 = p2[0], vi2 = p2[1];
            p2[0] = er; p2[1] = ei;      // exclusive pre-group state E_g
            float nr = fmaf(Tr, er, fmaf(-Ti, ei, vr2));
            float ni = fmaf(Ti, er, fmaf(Tr, ei, vi2));
            er = nr; ei = ni;
        }
    }
    __syncthreads();
    #pragma unroll
    for (int rr = 0; rr < 4; ++rr) {     // pass 2: per-element init states
        float2 E0 = *(const float2*)(Vs + (size_t)((bS)*8+g)*130 + 2*(4*tx+rr));
        float trr = E0.x, tii = E0.y;
        #pragma unroll
        for (int q = 0; q < 4; ++q) {
            float dr = d0R[rr][q], di = d0I[rr][q];
            d0R[rr][q] = trr; d0I[rr][q] = tii;
            float nr = fmaf(wc[rr], trr, fmaf(-wn[rr], tii, dr));
            float ni = fmaf(wn[rr], trr, fmaf(wc[rr], tii, di));
            trr = nr; tii = ni;
        }
        float2 E1 = *(const float2*)(Vs + (size_t)((2+bS)*8+g)*130 + 2*(4*tx+rr));
        trr = E1.x; tii = E1.y;
        #pragma unroll
        for (int q = 3; q >= 0; --q) {
            float dr = d1R[rr][q], di = d1I[rr][q];
            d1R[rr][q] = trr; d1I[rr][q] = tii;
            float nr = fmaf(wc[rr], trr, fmaf(-wn[rr], tii, dr));
            float ni = fmaf(wn[rr], trr, fmaf(wc[rr], tii, di));
            trr = nr; tii = ni;
        }
    }
    __syncthreads();
    // ---- Y GEMM, 5 phases (p0 Toeplitz B=Zs; p1..4 states staged from regs) ----
    int si = t & 63, kg = t >> 6;
    float2 pv[8];
    float acc[4][4] = {};
    for (int p = 0; p < 5; ++p) {
        if (p == 0) {
            #pragma unroll
            for (int q = 0; q < 16; ++q) {
                int kk = 16*kg + q;
                int d = si - kk;
                As[kk][si] = (d >= 0) ? ks0[d] : ks1[-d-1];
            }
        } else {
            const float* as_ = (p < 3) ? as0_ : as1_;
            const float* bs_ = (p < 3) ? bs0_ : bs1_;
            #pragma unroll
            for (int q = 0; q < 16; ++q) {
                int j = q >> 1;
                int n = 32*((p < 3) ? (p-1) : (p-3)) + 8*kg + j;
                float vx = pv[j].x, vy = pv[j].y;
                As[16*kg+q][si] = ((q&1) == 0) ? fmaf(as_[n], vx, bs_[n]*vy)
                                               : fmaf(bs_[n], vx, -as_[n]*vy);
            }
            if (p == 1 && tx < 8) {
                #pragma unroll
                for (int rr = 0; rr < 4; ++rr) {
                    int ml = 8*tx + 2*rr;
                    float4 vR; vR.x = d0R[rr][0]; vR.y = d0R[rr][1];
                    vR.z = d0R[rr][2]; vR.w = d0R[rr][3];
                    float4 vI; vI.x = d0I[rr][0]; vI.y = d0I[rr][1];
                    vI.z = d0I[rr][2]; vI.w = d0I[rr][3];
                    *(float4*)&Zs[ml][ZSW(ml, 4*ty)]     = vR;
                    *(float4*)&Zs[ml+1][ZSW(ml+1, 4*ty)] = vI;
                }
            } else if (p == 2 && tx >= 8) {
                #pragma unroll
                for (int rr = 0; rr < 4; ++rr) {
                    int ml = 8*(tx-8) + 2*rr;
                    float4 vR; vR.x = d0R[rr][0]; vR.y = d0R[rr][1];
                    vR.z = d0R[rr][2]; vR.w = d0R[rr][3];
                    float4 vI; vI.x = d0I[rr][0]; vI.y = d0I[rr][1];
                    vI.z = d0I[rr][2]; vI.w = d0I[rr][3];
                    *(float4*)&Zs[ml][ZSW(ml, 4*ty)]     = vR;
                    *(float4*)&Zs[ml+1][ZSW(ml+1, 4*ty)] = vI;
                }
            } else if (p == 3 && tx < 8) {
                #pragma unroll
                for (int rr = 0; rr < 4; ++rr) {
                    int ml = 8*tx + 2*rr;
                    float4 vR; vR.x = d1R[rr][0]; vR.y = d1R[rr][1];
                    vR.z = d1R[rr][2]; vR.w = d1R[rr][3];
                    float4 vI; vI.x = d1I[rr][0]; vI.y = d1I[rr][1];
                    vI.z = d1I[rr][2]; vI.w = d1I[rr][3];
                    *(float4*)&Zs[ml][ZSW(ml, 4*ty)]     = vR;
                    *(float4*)&Zs[ml+1][ZSW(ml+1, 4*ty)] = vI;
                }
            } else if (p == 4 && tx >= 8) {
                #pragma unroll
                for (int rr = 0; rr < 4; ++rr) {
                    int ml = 8*(tx-8) + 2*rr;
                    float4 vR; vR.x = d1R[rr][0]; vR.y = d1R[rr][1];
                    vR.z = d1R[rr][2]; vR.w = d1R[rr][3];
                    float4 vI; vI.x = d1I[rr][0]; vI.y = d1I[rr][1];
                    vI.z = d1I[rr][2]; vI.w = d1I[rr][3];
                    *(float4*)&Zs[ml][ZSW(ml, 4*ty)]     = vR;
                    *(float4*)&Zs[ml+1][ZSW(ml+1, 4*ty)] = vI;
                }
            }
        }
        __syncthreads();
        if (p < 4) {
            int pn = p + 1;
            int pp = (pn < 3) ? (pn-1) : (pn-3);
            int dsel = (pn < 3) ? (si + 1) : (63 - si);
            #pragma unroll
            for (int j2 = 0; j2 < 8; ++j2) {
                int n = 32*pp + 8*kg + j2;
                pv[j2] = *(const float2*)(pwTh + (size_t)n*132 + 2*dsel);
            }
        }
        #pragma unroll 8
        for (int kk = 0; kk < 64; ++kk) {
            float4 av = *(const float4*)&As[kk][4*tx];
            float4 bv = *(const float4*)&Zs[kk][ZSW(kk, 4*ty)];
            #pragma unroll
            for (int ii = 0; ii < 4; ++ii) {
                float a = (&av.x)[ii];
                acc[ii][0] = fmaf(a, bv.x, acc[ii][0]);
                acc[ii][1] = fmaf(a, bv.y, acc[ii][1]);
                acc[ii][2] = fmaf(a, bv.z, acc[ii][2]);
                acc[ii][3] = fmaf(a, bv.w, acc[ii][3]);
            }
        }
        __syncthreads();
    }
    float dv = Dv[h];
    #pragma unroll
    for (int q = 0; q < 4; ++q) {
        int cc2 = 4*ty + q;
        int b2 = 2*bp + (cc2 >> 5), ch2 = cc2 & 31;
        size_t base = ((size_t)b2 * Hq + h) * Lq + ch2 * 64 + 4 * tx;
        float4 zr = *(const float4*)(z + base);
        float vv[4];
        vv[0] = acc[0][q] + dv * zr.x;
        vv[1] = acc[1][q] + dv * zr.y;
        vv[2] = acc[2][q] + dv * zr.z;
        vv[3] = acc[3][q] + dv * zr.w;
        #pragma unroll
        for (int i = 0; i < 4; ++i) {
            float v = vv[i];
            float tt = tanhf(0.7978845608028654f * (v + 0.044715f * v * v * v));
            vv[i] = 0.5f * v * (1.0f + tt);
        }
        float4 r; r.x = vv[0]; r.y = vv[1]; r.z = vv[2]; r.w = vv[3];
        *(float4*)(u + base) = r;
    }
}

// ---------------------------------------------------------------------------
// Phase 5: out = bias + x + W@u.  (round-6/10 proven kernel, verbatim —
// measured at the LDS per-lane roofline: 64.5 of 69 TB/s)
// ---------------------------------------------------------------------------
__global__ __launch_bounds__(512, 4)
void gemm_kernel(const float* __restrict__ u, const float* __restrict__ W,
                 const float* __restrict__ bias, const float* __restrict__ x,
                 float* __restrict__ out) {
    int l0 = blockIdx.x * 64;
    int o0 = blockIdx.y * 128;
    int b  = blockIdx.z;
    int tid = threadIdx.x;
    __shared__ float Ws[2][32][132];
    __shared__ float Us[2][32][68];
    const float* ub = u + (size_t)b * Hq * Lq;
    float acc[4][4] = {};
    int wo = tid >> 4, wl = tid & 15;
    int sj = tid & 31, so = tid >> 5;
    int sl = tid & 63, sk = tid >> 6;
    float wreg[8], ureg[4];
    #pragma unroll
    for (int r = 0; r < 8; ++r) wreg[r] = W[(size_t)(o0 + so + 16*r) * Hq + sj];
    #pragma unroll
    for (int r = 0; r < 4; ++r) ureg[r] = ub[(size_t)(4*sk + r) * Lq + l0 + sl];
    #pragma unroll
    for (int r = 0; r < 8; ++r) Ws[0][sj][so + 16*r] = wreg[r];
    #pragma unroll
    for (int r = 0; r < 4; ++r) Us[0][4*sk + r][sl] = ureg[r];
    __syncthreads();
    for (int t = 0; t < Hq / 32; ++t) {
        int cur = t & 1;
        if (t < 15) {
            int k0 = (t + 1) * 32;
            #pragma unroll
            for (int r = 0; r < 8; ++r)
                wreg[r] = W[(size_t)(o0 + so + 16*r) * Hq + k0 + sj];
            #pragma unroll
            for (int r = 0; r < 4; ++r)
                ureg[r] = ub[(size_t)(k0 + 4*sk + r) * Lq + l0 + sl];
        }
        #pragma unroll 8
        for (int j = 0; j < 32; ++j) {
            float4 av = *(const float4*)&Ws[cur][j][4 * wo];
            float4 bv = *(const float4*)&Us[cur][j][4 * wl];
            #pragma unroll
            for (int io = 0; io < 4; ++io) {
                float a = (&av.x)[io];
                acc[io][0] = fmaf(a, bv.x, acc[io][0]);
                acc[io][1] = fmaf(a, bv.y, acc[io][1]);
                acc[io][2] = fmaf(a, bv.z, acc[io][2]);
                acc[io][3] = fmaf(a, bv.w, acc[io][3]);
            }
        }
        if (t < 15) {
            int nxt = cur ^ 1;
            #pragma unroll
            for (int r = 0; r < 8; ++r) Ws[nxt][sj][so + 16*r] = wreg[r];
            #pragma unroll
            for (int r = 0; r < 4; ++r) Us[nxt][4*sk + r][sl] = ureg[r];
        }
        __syncthreads();
    }
    #pragma unroll
    for (int io = 0; io < 4; ++io) {
        int o = o0 + 4 * wo + io;
        float bo = bias[o];
        size_t base = ((size_t)b * Hq + o) * Lq + l0 + 4 * wl;
        const float4 xr = *(const float4*)(x + base);
        float4 r;
        r.x = acc[io][0] + bo + xr.x;
        r.y = acc[io][1] + bo + xr.y;
        r.z = acc[io][2] + bo + xr.z;
        r.w = acc[io][3] + bo + xr.w;
        *(float4*)(out + base) = r;
    }
}

// ---------------------------------------------------------------------------
extern "C" void kernel_launch(void* const* d_in, const int* in_sizes, int n_in,
                              void* d_out, int out_size, void* d_ws, size_t ws_size,
                              hipStream_t stream) {
    (void)in_sizes; (void)n_in; (void)out_size; (void)ws_size;
    const float* x          = (const float*)d_in[0];
    const float* ln_w       = (const float*)d_in[1];
    const float* ln_b       = (const float*)d_in[2];
    const float* log_dt     = (const float*)d_in[3];
    const float* log_A_real = (const float*)d_in[4];
    const float* A_imag     = (const float*)d_in[5];
    const float* B_re       = (const float*)d_in[6];
    const float* B_im       = (const float*)d_in[7];
    const float* C_re       = (const float*)d_in[8];
    const float* C_im       = (const float*)d_in[9];
    const float* Dv         = (const float*)d_in[10];
    const float* W          = (const float*)d_in[11];
    const float* b_out      = (const float*)d_in[12];
    float* out = (float*)d_out;
    float* ws  = (float*)d_ws;

    const size_t BHL = (size_t)Bq * Hq * Lq;
    float* a0  = ws;
    float* b0  = ws + (size_t)PARAM;
    float* a1  = ws + 2 * (size_t)PARAM;
    float* b1  = ws + 3 * (size_t)PARAM;
    float* pw  = ws + 4 * (size_t)PARAM;           // 512*65*128 = 130*PARAM
    float* pwT = ws + 134 * (size_t)PARAM;         // 512*64*132 = 132*PARAM
    float* z   = ws + 266 * (size_t)PARAM;
    float* u   = z + BHL;

    setup_kernel<<<128 + Bq * (Lq / 64), 256, 0, stream>>>(
        log_dt, log_A_real, A_imag, B_re, B_im, C_re, C_im,
        a0, b0, a1, b1, pw, pwT, x, ln_w, ln_b, z);
    ssm_kernel<<<dim3(Hq, 2), 256, 0, stream>>>(z, pw, pwT, a0, b0, a1, b1,
                                                Dv, u);
    gemm_kernel<<<dim3(Lq / 64, Hq / 128, Bq), 512, 0, stream>>>(u, W, b_out, x, out);
}